// Round 2
// baseline (369.521 us; speedup 1.0000x reference)
//
#include <hip/hip_runtime.h>
#include <hip/hip_bf16.h>
#include <math.h>

// ---------------------------------------------------------------------------
// MultiHeadAttention: x[4,2048,1024] -> causal MHA (16 heads, d=64) -> out proj
// bf16 MFMA everywhere.
// R13: QKV GEMM = faithful 8-phase 256^2 template (m201 lineage):
// per phase {ds_read subtile || stage ONE half-tile (2 gll16) -> barrier ->
// lgkmcnt(0) -> setprio(1) 16 MFMA setprio(0) -> barrier}; counted vmcnt(4)
// ONLY at phases 4/8; stage lag-map: P1/2=A(t+1), P3/4=B(t+2), P5/6=A(t+2),
// P7/8=B(t+3). R12's coarse-phase variant was the documented m196 regression
// (stage burst at K-step end, no per-phase interleave) -- this fixes it.
// attn / prep / out-proj GEMM unchanged.
// ---------------------------------------------------------------------------

typedef __bf16  bf16x8  __attribute__((ext_vector_type(8)));
typedef __bf16  bf16x2  __attribute__((ext_vector_type(2)));
typedef float   floatx4 __attribute__((ext_vector_type(4)));
typedef short   shortx4 __attribute__((ext_vector_type(4)));

#if __has_builtin(__builtin_amdgcn_mfma_f32_16x16x16bf16_1k)
#define HAVE_MFMA16 1
#endif

__device__ __forceinline__ unsigned short f2bf(float f) {
    __hip_bfloat16 h = __float2bfloat16(f);
    return *reinterpret_cast<unsigned short*>(&h);
}

// pack two f32 -> 2xbf16 in one dword (HW packed cvt when available)
__device__ __forceinline__ unsigned int pkbf(float a, float b) {
#if __has_builtin(__builtin_amdgcn_cvt_pk_bf16_f32)
    bf16x2 t = __builtin_amdgcn_cvt_pk_bf16_f32(a, b);
    return __builtin_bit_cast(unsigned int, t);
#else
    return (unsigned int)f2bf(a) | ((unsigned int)f2bf(b) << 16);
#endif
}
__device__ __forceinline__ ushort4 pk4(float a, float b, float c, float d) {
    union { ushort4 u; unsigned int w[2]; } u;
    u.w[0] = pkbf(a, b);
    u.w[1] = pkbf(c, d);
    return u.u;
}

// async global->LDS, 16 B per lane; LDS dest = wave-uniform base + lane*16
__device__ __forceinline__ void gll16(const unsigned short* g, unsigned short* l) {
    __builtin_amdgcn_global_load_lds(
        (const __attribute__((address_space(1))) unsigned int*)g,
        (__attribute__((address_space(3))) unsigned int*)l, 16, 0, 0);
}

// --------------------------------------------- fused convert x + transpose W
__global__ void prep(const float* __restrict__ x, unsigned short* __restrict__ xb,
                     const float* __restrict__ Wq, const float* __restrict__ Wk,
                     const float* __restrict__ Wv, const float* __restrict__ Wo,
                     unsigned short* __restrict__ WT, unsigned short* __restrict__ WoT) {
    __shared__ float tile[32][33];
    int bid = blockIdx.x, tid = threadIdx.x;
    if (bid < 8192) {
        int i = (bid * 256 + tid) * 4;
        float4 v = *(const float4*)(x + i);
        *(ushort4*)(xb + i) = pk4(v.x, v.y, v.z, v.w);
        return;
    }
    int id = bid - 8192;
    int mat = id >> 10, rem = id & 1023;
    const float* src = (mat == 0) ? Wq : (mat == 1) ? Wk : (mat == 2) ? Wv : Wo;
    unsigned short* dst = (mat < 3) ? WT : WoT;
    int nbase = (mat < 3) ? mat * 1024 : 0;
    int kt = (rem & 31) * 32, nt = (rem >> 5) * 32;
    int tx = tid & 31, ty = tid >> 5;  // 32 x 8
    for (int j = 0; j < 32; j += 8)
        tile[ty + j][tx] = src[(kt + ty + j) * 1024 + nt + tx];
    __syncthreads();
    for (int j = 0; j < 32; j += 8) {
        int n = nt + ty + j;
        dst[(nbase + n) * 1024 + kt + tx] = f2bf(tile[tx][ty + j]);
    }
}

// ---------------------------------------------------------------- QKV GEMM
// C[8192,3072] = A[8192,1024] @ B^T (B stored [3072][1024]).
// 256x256 tile, BK=64, 512 threads / 8 waves (2M x 4N), per-wave 128x64.
// 8-phase schedule, one C-quadrant (64x32 of wave tile) x K=64 per phase.
#define PH_BAR do { asm volatile("" ::: "memory"); \
                    __builtin_amdgcn_s_barrier();  \
                    asm volatile("" ::: "memory"); } while (0)
#define LGKM0  asm volatile("s_waitcnt lgkmcnt(0)" ::: "memory")
#define VMC(N) asm volatile("s_waitcnt vmcnt(" #N ")" ::: "memory")

#define LDA_FRAG(SRC, dst, MQ)                                         \
    _Pragma("unroll") for (int ks_ = 0; ks_ < 2; ++ks_)                \
    _Pragma("unroll") for (int i_ = 0; i_ < 4; ++i_) {                 \
        int row_ = wm * 128 + (MQ) * 64 + i_ * 16 + lm;                \
        int pu_ = ((ks_ * 4 + quad) ^ (lm & 7)) * 8;                   \
        dst[ks_][i_] = *(const bf16x8*)&SRC[row_ * 64 + pu_];          \
    }

#define LDB_FRAG(SRC, dst, NQ)                                         \
    _Pragma("unroll") for (int ks_ = 0; ks_ < 2; ++ks_)                \
    _Pragma("unroll") for (int j_ = 0; j_ < 2; ++j_) {                 \
        int row_ = wn * 64 + (NQ) * 32 + j_ * 16 + lm;                 \
        int pu_ = ((ks_ * 4 + quad) ^ (lm & 7)) * 8;                   \
        dst[ks_][j_] = *(const bf16x8*)&SRC[row_ * 64 + pu_];          \
    }

#define MMA_Q(afr, bfr, MQ, NQ)                                                            \
    __builtin_amdgcn_s_setprio(1);                                                         \
    if (sw) {                                                                              \
        _Pragma("unroll") for (int i_ = 0; i_ < 4; ++i_)                                   \
        _Pragma("unroll") for (int j_ = 0; j_ < 2; ++j_) {                                 \
            floatx4& c_ = acc[(MQ) * 4 + i_][(NQ) * 2 + j_];                               \
            c_ = __builtin_amdgcn_mfma_f32_16x16x32_bf16(bfr[0][j_], afr[0][i_], c_, 0, 0, 0); \
            c_ = __builtin_amdgcn_mfma_f32_16x16x32_bf16(bfr[1][j_], afr[1][i_], c_, 0, 0, 0); \
        }                                                                                  \
    } else {                                                                               \
        _Pragma("unroll") for (int i_ = 0; i_ < 4; ++i_)                                   \
        _Pragma("unroll") for (int j_ = 0; j_ < 2; ++j_) {                                 \
            floatx4& c_ = acc[(MQ) * 4 + i_][(NQ) * 2 + j_];                               \
            c_ = __builtin_amdgcn_mfma_f32_16x16x32_bf16(afr[0][i_], bfr[0][j_], c_, 0, 0, 0); \
            c_ = __builtin_amdgcn_mfma_f32_16x16x32_bf16(afr[1][i_], bfr[1][j_], c_, 0, 0, 0); \
        }                                                                                  \
    }                                                                                      \
    __builtin_amdgcn_s_setprio(0);

__global__ __launch_bounds__(512, 2) void gemm_qkv(const unsigned short* __restrict__ A,
                                                   const unsigned short* __restrict__ B,
                                                   unsigned short* __restrict__ Qo,
                                                   unsigned short* __restrict__ Ko,
                                                   unsigned short* __restrict__ Vo) {
    __shared__ __align__(16) unsigned short As[2][256 * 64];
    __shared__ __align__(16) unsigned short Bs[2][256 * 64];

    int tid = threadIdx.x;
    int lane = tid & 63, w = tid >> 6;       // 8 waves
    int wm = w >> 2, wn = w & 3;             // 2 x 4 wave grid, wave tile 128x64
    int lm = lane & 15, quad = lane >> 4;

    // XCD swizzle: 8 XCD chunks arranged 4(m) x 2(n); per-XCD working set
    // = 8 A-panels (4 MB) + 6 B-panels (3 MB). im-fastest shares B panel.
    int bid = blockIdx.x;
    int xcd = bid & 7, idx = bid >> 3;       // 48 blocks per XCD
    int cm = xcd & 3, cn = xcd >> 2;
    int im = idx & 7, in_ = idx >> 3;        // 8 x 6 within chunk
    int bm = cm * 8 + im, bn = cn * 6 + in_;
    int m0 = bm * 256, n0 = bn * 256;
    bool sw = (n0 < 2048);                   // C^T orientation for Q/K columns

    const unsigned short* Ag = A + (size_t)m0 * 1024;
    const unsigned short* Bg = B + (size_t)n0 * 1024;
    unsigned short* As0 = &As[0][0]; unsigned short* As1 = &As[1][0];
    unsigned short* Bs0 = &Bs[0][0]; unsigned short* Bs1 = &Bs[1][0];

    // stage ONE half-tile (128 rows x 64 cols) = 2 gll16/thread.
    // Linear LDS dest; XOR-swizzled SOURCE column (involution, read applies same XOR).
    auto STG = [&](unsigned short* L, const unsigned short* G, int kb, int half) {
#pragma unroll
        for (int p = 0; p < 2; ++p) {
            int id = p * 512 + tid;                       // 0..1023
            int row = half * 128 + (id >> 3);             // tile row
            int cbs = ((id & 7) ^ (row & 7)) * 8;         // swizzled src unit
            gll16(&G[row * 1024 + kb + cbs],
                  &L[half * 8192 + (p * 512 + w * 64) * 8]);  // wave-uniform base
        }
    };

    floatx4 acc[8][4] = {};

    // prologue: tile0 full (buf0) + tile1 B-halves (buf1); wait tile0 only.
    STG(As0, Ag, 0, 0);  STG(As0, Ag, 0, 1);
    STG(Bs0, Bg, 0, 0);  STG(Bs0, Bg, 0, 1);
    STG(Bs1, Bg, 64, 0); STG(Bs1, Bg, 64, 1);
    VMC(4);
    PH_BAR;

#pragma unroll 1
    for (int i = 0; i < 7; ++i) {
        int k1 = (2 * i + 1) * 64, k2 = (2 * i + 2) * 64, k3 = (2 * i + 3) * 64;
        bf16x8 a0[2][4], a1[2][4], b0[2][2], b1[2][2];

        // ---------------- tile 2i from buf0 ----------------
        // P1: ds a0+b0 (12 reads) || stage A-lo(t+1)->buf1
        LDA_FRAG(As0, a0, 0); LDB_FRAG(Bs0, b0, 0);
        STG(As1, Ag, k1, 0);
        PH_BAR; LGKM0; MMA_Q(a0, b0, 0, 0); PH_BAR;
        // P2: ds b1 || stage A-hi(t+1)
        LDB_FRAG(Bs0, b1, 1);
        STG(As1, Ag, k1, 1);
        PH_BAR; LGKM0; MMA_Q(a0, b1, 0, 1); PH_BAR;
        // P3: ds a1 || stage B-lo(t+2)->buf0  (buf0.B sealed by P2 barrier)
        LDA_FRAG(As0, a1, 1);
        STG(Bs0, Bg, k2, 0);
        PH_BAR; LGKM0; MMA_Q(a1, b1, 1, 1); PH_BAR;
        // P4: stage B-hi(t+2); counted vmcnt(4) proves tile t+1 resident
        STG(Bs0, Bg, k2, 1);
        PH_BAR; MMA_Q(a1, b0, 1, 0);
        VMC(4);
        PH_BAR;

        // ---------------- tile 2i+1 from buf1 ----------------
        // P5: ds a0+b0 || stage A-lo(t+2)->buf0 (buf0.A sealed by P3 barrier)
        LDA_FRAG(As1, a0, 0); LDB_FRAG(Bs1, b0, 0);
        STG(As0, Ag, k2, 0);
        PH_BAR; LGKM0; MMA_Q(a0, b0, 0, 0); PH_BAR;
        // P6: ds b1 || stage A-hi(t+2)
        LDB_FRAG(Bs1, b1, 1);
        STG(As0, Ag, k2, 1);
        PH_BAR; LGKM0; MMA_Q(a0, b1, 0, 1); PH_BAR;
        // P7: ds a1 || stage B-lo(t+3)->buf1 (buf1.B sealed by P6 barrier)
        LDA_FRAG(As1, a1, 1);
        STG(Bs1, Bg, k3, 0);
        PH_BAR; LGKM0; MMA_Q(a1, b1, 1, 1); PH_BAR;
        // P8: stage B-hi(t+3); counted vmcnt(4) proves tile t+2 resident
        STG(Bs1, Bg, k3, 1);
        PH_BAR; MMA_Q(a1, b0, 1, 0);
        VMC(4);
        PH_BAR;
    }

    {   // ---------------- peeled tail: tiles 14, 15 ----------------
        bf16x8 a0[2][4], a1[2][4], b0[2][2], b1[2][2];
        // tile 14 from buf0; stage A(15)->buf1 at P1/P2; drain at P4.
        LDA_FRAG(As0, a0, 0); LDB_FRAG(Bs0, b0, 0);
        STG(As1, Ag, 15 * 64, 0);
        PH_BAR; LGKM0; MMA_Q(a0, b0, 0, 0); PH_BAR;
        LDB_FRAG(Bs0, b1, 1);
        STG(As1, Ag, 15 * 64, 1);
        PH_BAR; LGKM0; MMA_Q(a0, b1, 0, 1); PH_BAR;
        LDA_FRAG(As0, a1, 1);
        PH_BAR; LGKM0; MMA_Q(a1, b1, 1, 1);
        MMA_Q(a1, b0, 1, 0);
        VMC(0);
        PH_BAR;
        // tile 15 from buf1: straight (no stages, no barriers needed after)
        LDA_FRAG(As1, a0, 0); LDB_FRAG(Bs1, b0, 0);
        LDB_FRAG(Bs1, b1, 1); LDA_FRAG(As1, a1, 1);
        MMA_Q(a0, b0, 0, 0); MMA_Q(a0, b1, 0, 1);
        MMA_Q(a1, b1, 1, 1); MMA_Q(a1, b0, 1, 0);
    }

    if (sw) {
        // C^T layout: lane owns seq s (col=lm) and 4 consecutive out-cols.
        bool isQ = (n0 < 1024);
        unsigned short* dst = isQ ? Qo : Ko;
        float qs = isQ ? 0.1803368801f : 1.0f;  // 1/8 * log2(e)
#pragma unroll
        for (int mi = 0; mi < 8; ++mi) {
            int s = m0 + wm * 128 + mi * 16 + lm;
            int bb = s >> 11, sl = s & 2047;
#pragma unroll
            for (int ni = 0; ni < 4; ++ni) {
                int gcol0 = n0 + wn * 64 + ni * 16 + quad * 4;
                int h = (gcol0 & 1023) >> 6, d0 = gcol0 & 63;
                *(ushort4*)&dst[(((size_t)(bb * 16 + h) * 2048) + sl) * 64 + d0] =
                    pk4(acc[mi][ni][0] * qs, acc[mi][ni][1] * qs,
                        acc[mi][ni][2] * qs, acc[mi][ni][3] * qs);
            }
        }
    } else {
        // V columns, normal layout: packed along seq for V^T [bh][d][2048].
#pragma unroll
        for (int mi = 0; mi < 8; ++mi) {
            int grow0 = m0 + wm * 128 + mi * 16 + quad * 4;
            int bb = grow0 >> 11, sl = grow0 & 2047;
#pragma unroll
            for (int ni = 0; ni < 4; ++ni) {
                int gcol = n0 + wn * 64 + ni * 16 + lm;
                int hn = gcol & 1023;
                int h = hn >> 6, d = hn & 63;
                *(ushort4*)&Vo[((size_t)(bb * 16 + h) * 64 + d) * 2048 + sl] =
                    pk4(acc[mi][ni][0], acc[mi][ni][1], acc[mi][ni][2], acc[mi][ni][3]);
            }
        }
    }
}

// ---------------------------------------------------------------- GEMM B^T
// (out-proj only) C[M,N] = A[M,1024] @ B^T. 128x128 tile, BK=64.
template <int EPI>
__global__ __launch_bounds__(256) void gemm_bt(const unsigned short* __restrict__ A,
                                               const unsigned short* __restrict__ B,
                                               unsigned short* __restrict__ Qo,
                                               unsigned short* __restrict__ Ko,
                                               unsigned short* __restrict__ Vo,
                                               const float* __restrict__ bias,
                                               float* __restrict__ Out) {
    __shared__ __align__(16) unsigned short As[128 * 64];
    __shared__ __align__(16) unsigned short Bs[128 * 64];

    int tid = threadIdx.x;
    int lane = tid & 63, w = tid >> 6;
    int wm = w >> 1, wn = w & 1;
    int lm = lane & 15, quad = lane >> 4;
    int m0 = blockIdx.x * 128, n0 = blockIdx.y * 128;
    bool sw = (EPI == 1) || (n0 < 2048);  // block-uniform orientation

    floatx4 acc[4][4] = {};

    for (int kb = 0; kb < 1024; kb += 64) {
        __syncthreads();
        for (int p = 0; p < 4; ++p) {
            int id = p * 256 + tid;
            int row = id >> 3;
            int cbs = ((id & 7) ^ (row & 7)) * 8;  // XOR-swizzled source unit
            int lbase = (p * 256 + w * 64) * 8;    // wave-uniform; HW adds lane*16B
            gll16(&A[(m0 + row) * 1024 + kb + cbs], &As[lbase]);
            gll16(&B[(n0 + row) * 1024 + kb + cbs], &Bs[lbase]);
        }
        __syncthreads();
        bf16x8 af[2][4], bf[2][4];
        for (int ks = 0; ks < 2; ++ks)
            for (int i = 0; i < 4; ++i) {
                int pu = (((ks * 4 + quad) ^ (lm & 7))) * 8;  // swizzled unit
                af[ks][i] = *(const bf16x8*)&As[(wm * 64 + i * 16 + lm) * 64 + pu];
                bf[ks][i] = *(const bf16x8*)&Bs[(wn * 64 + i * 16 + lm) * 64 + pu];
            }
        if (sw) {
            for (int mi = 0; mi < 4; ++mi)
                for (int ni = 0; ni < 4; ++ni) {
                    acc[mi][ni] = __builtin_amdgcn_mfma_f32_16x16x32_bf16(bf[0][ni], af[0][mi], acc[mi][ni], 0, 0, 0);
                    acc[mi][ni] = __builtin_amdgcn_mfma_f32_16x16x32_bf16(bf[1][ni], af[1][mi], acc[mi][ni], 0, 0, 0);
                }
        } else {
            for (int mi = 0; mi < 4; ++mi)
                for (int ni = 0; ni < 4; ++ni) {
                    acc[mi][ni] = __builtin_amdgcn_mfma_f32_16x16x32_bf16(af[0][mi], bf[0][ni], acc[mi][ni], 0, 0, 0);
                    acc[mi][ni] = __builtin_amdgcn_mfma_f32_16x16x32_bf16(af[1][mi], bf[1][ni], acc[mi][ni], 0, 0, 0);
                }
        }
    }

    if constexpr (EPI == 0) {
        if (sw) {
            bool isQ = (n0 < 1024);
            unsigned short* dst = isQ ? Qo : Ko;
            float qs = isQ ? 0.1803368801f : 1.0f;  // 1/8 * log2(e)
            for (int mi = 0; mi < 4; ++mi) {
                int s = m0 + wm * 64 + mi * 16 + lm;
                int bb = s >> 11, sl = s & 2047;
                for (int ni = 0; ni < 4; ++ni) {
                    int gcol0 = n0 + wn * 64 + ni * 16 + quad * 4;
                    int h = (gcol0 & 1023) >> 6, d0 = gcol0 & 63;
                    *(ushort4*)&dst[(((size_t)(bb * 16 + h) * 2048) + sl) * 64 + d0] =
                        pk4(acc[mi][ni][0] * qs, acc[mi][ni][1] * qs,
                            acc[mi][ni][2] * qs, acc[mi][ni][3] * qs);
                }
            }
        } else {
            for (int mi = 0; mi < 4; ++mi) {
                int grow0 = m0 + wm * 64 + mi * 16 + quad * 4;
                int bb = grow0 >> 11, sl = grow0 & 2047;
                for (int ni = 0; ni < 4; ++ni) {
                    int gcol = n0 + wn * 64 + ni * 16 + lm;
                    int hn = gcol & 1023;
                    int h = hn >> 6, d = hn & 63;
                    *(ushort4*)&Vo[((size_t)(bb * 16 + h) * 64 + d) * 2048 + sl] =
                        pk4(acc[mi][ni][0], acc[mi][ni][1], acc[mi][ni][2], acc[mi][ni][3]);
                }
            }
        }
    } else {
        // out-proj: C^T layout -> float4 stores + float4 bias loads
        for (int mi = 0; mi < 4; ++mi) {
            int s = m0 + wm * 64 + mi * 16 + lm;
            for (int ni = 0; ni < 4; ++ni) {
                int gcol0 = n0 + wn * 64 + ni * 16 + quad * 4;
                float4 bv = *(const float4*)&bias[gcol0];
                float4 o;
                o.x = acc[mi][ni][0] + bv.x; o.y = acc[mi][ni][1] + bv.y;
                o.z = acc[mi][ni][2] + bv.z; o.w = acc[mi][ni][3] + bv.w;
                *(float4*)&Out[(size_t)s * 1024 + gcol0] = o;
            }
        }
    }
}

// ------------------------------------------------------------- attention
// Flat grid 1024 = (qt heavy-first, 16 tiles of 128 q) x 64 bh.
// 512 thr = 8 waves x 16 q-rows. KB=64. S^T orientation: q=lm, k=quad*4+r.
// NO-MAX softmax; Q pre-scaled; lrow reduced once at the end.
__global__ __launch_bounds__(512) void attn(const unsigned short* __restrict__ Q,
                                            const unsigned short* __restrict__ K,
                                            const unsigned short* __restrict__ Vt,
                                            unsigned short* __restrict__ ctx) {
    constexpr int LKS = 72;
    __shared__ __align__(16) unsigned short Ks[2][64 * LKS];
    __shared__ __align__(16) unsigned short Vts[2][64 * LKS];

    int tid = threadIdx.x, lane = tid & 63, w = tid >> 6;   // w: 0..7
    int lm = lane & 15, quad = lane >> 4;
    int blk = blockIdx.x;
    int bh = blk & 63;
    int qt = 15 - (blk >> 6);   // LPT: heaviest q-tiles dispatch first
    int trips = 2 * qt + 2;
    int tmax = 2 * qt + (w >> 2);  // last trip this wave computes
    const unsigned short* Qg  = Q  + (size_t)bh * 2048 * 64;
    const unsigned short* Kg  = K  + (size_t)bh * 2048 * 64;
    const unsigned short* Vtg = Vt + (size_t)bh * 64 * 2048;

    int qrow = qt * 128 + w * 16 + lm;
    bf16x8 aq0 = *(const bf16x8*)&Qg[qrow * 64 + quad * 8];
    bf16x8 aq1 = *(const bf16x8*)&Qg[qrow * 64 + 32 + quad * 8];

    floatx4 O[4] = {};            // O^T: per dblk, lane holds d=quad*4+r, q=lm
    float lrow = 0.f;

    int r0 = tid >> 3, c0 = (tid & 7) * 8;  // 512 thr -> rows 0..63, 1 uint4 each

    {   // prologue: stage tile 0 into buffer 0
        uint4 k0 = *(const uint4*)&Kg[r0 * 64 + c0];
        uint4 v0 = *(const uint4*)&Vtg[r0 * 2048 + c0];
        *(uint4*)&Ks[0][r0 * LKS + c0]  = k0;
        *(uint4*)&Vts[0][r0 * LKS + c0] = v0;
    }
    __syncthreads();

    for (int t = 0; t < trips; ++t) {
        int cur = t & 1, nxt = cur ^ 1;
        bool pre = (t + 1 < trips);
        uint4 pk, pv;
        if (pre) {  // issue next tile's loads NOW; they complete under compute
            int kb2 = (t + 1) * 64;
            pk = *(const uint4*)&Kg[(kb2 + r0) * 64 + c0];
            pv = *(const uint4*)&Vtg[r0 * 2048 + kb2 + c0];
        }

        if (t <= tmax) {  // wave-uniform; barriers are outside this branch
            const unsigned short* Kc = Ks[cur];
            const unsigned short* Vc = Vts[cur];

            floatx4 s[4];
            for (int n = 0; n < 4; ++n) {
                bf16x8 a0 = *(const bf16x8*)&Kc[(n * 16 + lm) * LKS + quad * 8];
                bf16x8 a1 = *(const bf16x8*)&Kc[(n * 16 + lm) * LKS + 32 + quad * 8];
                floatx4 z = {};
                z = __builtin_amdgcn_mfma_f32_16x16x32_bf16(a0, aq0, z, 0, 0, 0);
                z = __builtin_amdgcn_mfma_f32_16x16x32_bf16(a1, aq1, z, 0, 0, 0);
                s[n] = z;
            }

            bool diag = (t == tmax);
            if (diag) {
                int qr = (w & 3) * 16 + lm;  // q - kb on this wave's diag tile
                for (int n = 0; n < 4; ++n)
                    for (int r = 0; r < 4; ++r)
                        if (n * 16 + quad * 4 + r > qr) s[n][r] = -INFINITY;
            }
            float p[4][4], rs = 0.f;
            for (int n = 0; n < 4; ++n)
                for (int r = 0; r < 4; ++r) {
                    p[n][r] = __builtin_amdgcn_exp2f(s[n][r]);
                    rs += p[n][r];
                }
            lrow += rs;

#ifdef HAVE_MFMA16
            // P^T is ALREADY the 16x16x16 B-frag (B[k=quad*4+i][n=lm]) — no LDS.
            shortx4 pb[4];
            for (int n = 0; n < 4; ++n) {
                union { shortx4 s4; unsigned int w2[2]; } u;
                u.w2[0] = pkbf(p[n][0], p[n][1]);
                u.w2[1] = pkbf(p[n][2], p[n][3]);
                pb[n] = u.s4;
            }
            for (int dblk = 0; dblk < 4; ++dblk)
                for (int n = 0; n < 4; ++n) {
                    shortx4 va = *(const shortx4*)&Vc[(dblk * 16 + lm) * LKS + n * 16 + quad * 4];
                    O[dblk] = __builtin_amdgcn_mfma_f32_16x16x16bf16_1k(va, pb[n], O[dblk], 0, 0, 0);
                }
#else
            unsigned int dw[4][2];
            for (int n = 0; n < 4; ++n) {
                dw[n][0] = pkbf(p[n][0], p[n][1]);
                dw[n][1] = pkbf(p[n][2], p[n][3]);
            }
            bool hiTile = (quad >> 1);
            for (int hh = 0; hh < 2; ++hh) {
                unsigned int bp[4];
                for (int j = 0; j < 4; ++j) {
                    int srcLane = lm + (((quad & 1) * 2 + (j >> 1)) << 4);
                    unsigned int lo = __shfl((int)dw[2 * hh][j & 1], srcLane);
                    unsigned int hi = __shfl((int)dw[2 * hh + 1][j & 1], srcLane);
                    bp[j] = hiTile ? hi : lo;
                }
                bf16x8 bfrag = *(bf16x8*)bp;
                for (int dblk = 0; dblk < 4; ++dblk) {
                    bf16x8 av = *(const bf16x8*)&Vc[(dblk * 16 + lm) * LKS + hh * 32 + quad * 8];
                    O[dblk] = __builtin_amdgcn_mfma_f32_16x16x32_bf16(av, bfrag, O[dblk], 0, 0, 0);
                }
            }
#endif
        }

        if (pre) {  // loads completed under compute; write into other buffer
            *(uint4*)&Ks[nxt][r0 * LKS + c0]  = pk;
            *(uint4*)&Vts[nxt][r0 * LKS + c0] = pv;
        }
        __syncthreads();
    }

    // reduce lrow across the 4 lane-groups holding the same q (once)
    lrow += __shfl_xor(lrow, 16);
    lrow += __shfl_xor(lrow, 32);

    int b = bh >> 4, h = bh & 15;
    int q = qt * 128 + w * 16 + lm;
    float inv = 1.0f / lrow;
    for (int dblk = 0; dblk < 4; ++dblk) {
        *(ushort4*)&ctx[((size_t)(b * 2048 + q)) * 1024 + h * 64 + dblk * 16 + quad * 4] =
            pk4(O[dblk][0] * inv, O[dblk][1] * inv, O[dblk][2] * inv, O[dblk][3] * inv);
    }
}

// ---------------------------------------------------------------- launch
extern "C" void kernel_launch(void* const* d_in, const int* in_sizes, int n_in,
                              void* d_out, int out_size, void* d_ws, size_t ws_size,
                              hipStream_t stream) {
    const float* x   = (const float*)d_in[0];
    const float* Wq  = (const float*)d_in[1];
    const float* Wk  = (const float*)d_in[2];
    const float* Wv  = (const float*)d_in[3];
    const float* Wo  = (const float*)d_in[4];
    const float* bo  = (const float*)d_in[5];
    float* out = (float*)d_out;

    char* ws = (char*)d_ws;
    unsigned short* xb  = (unsigned short*)(ws);               // 16 MB (dead after gemm_qkv)
    unsigned short* WT  = (unsigned short*)(ws + 16777216);    // 6 MB
    unsigned short* WoT = (unsigned short*)(ws + 23068672);    // 2 MB
    unsigned short* Qb  = (unsigned short*)(ws + 25165824);    // 16 MB
    unsigned short* Kb  = (unsigned short*)(ws + 41943040);    // 16 MB
    unsigned short* Vtb = (unsigned short*)(ws + 58720256);    // 16 MB (transposed)
    unsigned short* ctx = xb;                                  // alias: xb is dead

    prep<<<12288, 256, 0, stream>>>(x, xb, Wq, Wk, Wv, Wo, WT, WoT);
    gemm_qkv<<<384, 512, 0, stream>>>(xb, WT, Qb, Kb, Vtb);
    attn<<<1024, 512, 0, stream>>>(Qb, Kb, Vtb, ctx);
    gemm_bt<1><<<dim3(64, 8), 256, 0, stream>>>(ctx, WoT, nullptr, nullptr, nullptr, bo, out);
}

// Round 3
// 254.227 us; speedup vs baseline: 1.4535x; 1.4535x over previous
//
#include <hip/hip_runtime.h>
#include <hip/hip_bf16.h>
#include <math.h>

// ---------------------------------------------------------------------------
// MultiHeadAttention: x[4,2048,1024] -> causal MHA (16 heads, d=64) -> out proj
// bf16 MFMA everywhere.
// R14: REVERT to the verified R0/253.7us structure (m97-style 128^2 GEMMs,
// S^T-orientation attention). The 8-phase 256^2 rewrites (R12/R13) regressed:
// R12 = m196 coarse-phase regression; R13 = scratch-spill pathology
// (WRITE_SIZE 4x output, VALUBusy 4.9%). Abandoned.
// ONE new lever vs R0: T1 XCD-chunked bijective block swizzle on both GEMMs
// (each XCD owns an 8-m-block band; A band = 2 MB fits per-XCD L2).
// ---------------------------------------------------------------------------

typedef __bf16  bf16x8  __attribute__((ext_vector_type(8)));
typedef __bf16  bf16x2  __attribute__((ext_vector_type(2)));
typedef float   floatx4 __attribute__((ext_vector_type(4)));
typedef short   shortx4 __attribute__((ext_vector_type(4)));

#if __has_builtin(__builtin_amdgcn_mfma_f32_16x16x16bf16_1k)
#define HAVE_MFMA16 1
#endif

__device__ __forceinline__ unsigned short f2bf(float f) {
    __hip_bfloat16 h = __float2bfloat16(f);
    return *reinterpret_cast<unsigned short*>(&h);
}

// pack two f32 -> 2xbf16 in one dword (HW packed cvt when available)
__device__ __forceinline__ unsigned int pkbf(float a, float b) {
#if __has_builtin(__builtin_amdgcn_cvt_pk_bf16_f32)
    bf16x2 t = __builtin_amdgcn_cvt_pk_bf16_f32(a, b);
    return __builtin_bit_cast(unsigned int, t);
#else
    return (unsigned int)f2bf(a) | ((unsigned int)f2bf(b) << 16);
#endif
}
__device__ __forceinline__ ushort4 pk4(float a, float b, float c, float d) {
    union { ushort4 u; unsigned int w[2]; } u;
    u.w[0] = pkbf(a, b);
    u.w[1] = pkbf(c, d);
    return u.u;
}

// async global->LDS, 16 B per lane; LDS dest = wave-uniform base + lane*16
__device__ __forceinline__ void gll16(const unsigned short* g, unsigned short* l) {
    __builtin_amdgcn_global_load_lds(
        (const __attribute__((address_space(1))) unsigned int*)g,
        (__attribute__((address_space(3))) unsigned int*)l, 16, 0, 0);
}

// --------------------------------------------- fused convert x + transpose W
__global__ void prep(const float* __restrict__ x, unsigned short* __restrict__ xb,
                     const float* __restrict__ Wq, const float* __restrict__ Wk,
                     const float* __restrict__ Wv, const float* __restrict__ Wo,
                     unsigned short* __restrict__ WT, unsigned short* __restrict__ WoT) {
    __shared__ float tile[32][33];
    int bid = blockIdx.x, tid = threadIdx.x;
    if (bid < 8192) {
        int i = (bid * 256 + tid) * 4;
        float4 v = *(const float4*)(x + i);
        *(ushort4*)(xb + i) = pk4(v.x, v.y, v.z, v.w);
        return;
    }
    int id = bid - 8192;
    int mat = id >> 10, rem = id & 1023;
    const float* src = (mat == 0) ? Wq : (mat == 1) ? Wk : (mat == 2) ? Wv : Wo;
    unsigned short* dst = (mat < 3) ? WT : WoT;
    int nbase = (mat < 3) ? mat * 1024 : 0;
    int kt = (rem & 31) * 32, nt = (rem >> 5) * 32;
    int tx = tid & 31, ty = tid >> 5;  // 32 x 8
    for (int j = 0; j < 32; j += 8)
        tile[ty + j][tx] = src[(kt + ty + j) * 1024 + nt + tx];
    __syncthreads();
    for (int j = 0; j < 32; j += 8) {
        int n = nt + ty + j;
        dst[(nbase + n) * 1024 + kt + tx] = f2bf(tile[tx][ty + j]);
    }
}

// ---------------------------------------------------------------- GEMM B^T
// C[M,N] = A[M,1024] @ B^T (B stored [N][1024]). 128x128 tile, BK=64.
// Single-buffer gll16 staging with XOR swizzle (0 bank conflicts).
// Flat grid + XCD-chunked bijective swizzle: XCD (bid&7) owns an 8-m-block
// band (2 MB of A, L2-resident) x all n-blocks. NBLK = n-blocks.
// Orientation: swapped (C^T) for Q/K columns (n0<2048) and all of EPI1.
template <int EPI, int NBLK>
__global__ __launch_bounds__(256) void gemm_bt(const unsigned short* __restrict__ A,
                                               const unsigned short* __restrict__ B,
                                               unsigned short* __restrict__ Qo,
                                               unsigned short* __restrict__ Ko,
                                               unsigned short* __restrict__ Vo,
                                               const float* __restrict__ bias,
                                               float* __restrict__ Out) {
    __shared__ __align__(16) unsigned short As[128 * 64];
    __shared__ __align__(16) unsigned short Bs[128 * 64];

    int tid = threadIdx.x;
    int lane = tid & 63, w = tid >> 6;
    int wm = w >> 1, wn = w & 1;
    int lm = lane & 15, quad = lane >> 4;
    // T1 swizzle: bid&7 -> XCD chunk; within chunk m-fastest over the 8-band.
    int bid = blockIdx.x;
    int xcd = bid & 7, ic = bid >> 3;
    int bm = xcd * 8 + (ic & 7), bn = ic >> 3;  // bn in [0, NBLK)
    int m0 = bm * 128, n0 = bn * 128;
    bool sw = (EPI == 1) || (n0 < 2048);  // block-uniform orientation

    floatx4 acc[4][4] = {};

    for (int kb = 0; kb < 1024; kb += 64) {
        __syncthreads();
        for (int p = 0; p < 4; ++p) {
            int id = p * 256 + tid;
            int row = id >> 3;
            int cbs = ((id & 7) ^ (row & 7)) * 8;  // XOR-swizzled source unit
            int lbase = (p * 256 + w * 64) * 8;    // wave-uniform; HW adds lane*16B
            gll16(&A[(m0 + row) * 1024 + kb + cbs], &As[lbase]);
            gll16(&B[(n0 + row) * 1024 + kb + cbs], &Bs[lbase]);
        }
        __syncthreads();
        bf16x8 af[2][4], bf[2][4];
        for (int ks = 0; ks < 2; ++ks)
            for (int i = 0; i < 4; ++i) {
                int pu = (((ks * 4 + quad) ^ (lm & 7))) * 8;  // swizzled unit
                af[ks][i] = *(const bf16x8*)&As[(wm * 64 + i * 16 + lm) * 64 + pu];
                bf[ks][i] = *(const bf16x8*)&Bs[(wn * 64 + i * 16 + lm) * 64 + pu];
            }
        if (sw) {
            for (int mi = 0; mi < 4; ++mi)
                for (int ni = 0; ni < 4; ++ni) {
                    acc[mi][ni] = __builtin_amdgcn_mfma_f32_16x16x32_bf16(bf[0][ni], af[0][mi], acc[mi][ni], 0, 0, 0);
                    acc[mi][ni] = __builtin_amdgcn_mfma_f32_16x16x32_bf16(bf[1][ni], af[1][mi], acc[mi][ni], 0, 0, 0);
                }
        } else {
            for (int mi = 0; mi < 4; ++mi)
                for (int ni = 0; ni < 4; ++ni) {
                    acc[mi][ni] = __builtin_amdgcn_mfma_f32_16x16x32_bf16(af[0][mi], bf[0][ni], acc[mi][ni], 0, 0, 0);
                    acc[mi][ni] = __builtin_amdgcn_mfma_f32_16x16x32_bf16(af[1][mi], bf[1][ni], acc[mi][ni], 0, 0, 0);
                }
        }
    }

    if constexpr (EPI == 0) {
        if (sw) {
            // C^T layout: lane owns seq s (col=lm) and 4 consecutive out-cols.
            bool isQ = (n0 < 1024);
            unsigned short* dst = isQ ? Qo : Ko;
            float qs = isQ ? 0.1803368801f : 1.0f;  // 1/8 * log2(e)
            for (int mi = 0; mi < 4; ++mi) {
                int s = m0 + wm * 64 + mi * 16 + lm;
                int bb = s >> 11, sl = s & 2047;
                for (int ni = 0; ni < 4; ++ni) {
                    int gcol0 = n0 + wn * 64 + ni * 16 + quad * 4;
                    int h = (gcol0 & 1023) >> 6, d0 = gcol0 & 63;
                    *(ushort4*)&dst[(((size_t)(bb * 16 + h) * 2048) + sl) * 64 + d0] =
                        pk4(acc[mi][ni][0] * qs, acc[mi][ni][1] * qs,
                            acc[mi][ni][2] * qs, acc[mi][ni][3] * qs);
                }
            }
        } else {
            // V columns, normal layout: packed along seq for V^T [bh][d][2048].
            for (int mi = 0; mi < 4; ++mi) {
                int grow0 = m0 + wm * 64 + mi * 16 + quad * 4;
                int bb = grow0 >> 11, sl = grow0 & 2047;
                for (int ni = 0; ni < 4; ++ni) {
                    int gcol = n0 + wn * 64 + ni * 16 + lm;
                    int hn = gcol & 1023;
                    int h = hn >> 6, d = hn & 63;
                    *(ushort4*)&Vo[((size_t)(bb * 16 + h) * 64 + d) * 2048 + sl] =
                        pk4(acc[mi][ni][0], acc[mi][ni][1], acc[mi][ni][2], acc[mi][ni][3]);
                }
            }
        }
    } else {
        // out-proj: C^T layout -> float4 stores + float4 bias loads
        for (int mi = 0; mi < 4; ++mi) {
            int s = m0 + wm * 64 + mi * 16 + lm;
            for (int ni = 0; ni < 4; ++ni) {
                int gcol0 = n0 + wn * 64 + ni * 16 + quad * 4;
                float4 bv = *(const float4*)&bias[gcol0];
                float4 o;
                o.x = acc[mi][ni][0] + bv.x; o.y = acc[mi][ni][1] + bv.y;
                o.z = acc[mi][ni][2] + bv.z; o.w = acc[mi][ni][3] + bv.w;
                *(float4*)&Out[(size_t)s * 1024 + gcol0] = o;
            }
        }
    }
}

// ------------------------------------------------------------- attention
// Flat grid 1024 = (qt heavy-first, 16 tiles of 128 q) x 64 bh.
// 512 thr = 8 waves x 16 q-rows. KB=64. S^T orientation: q=lm, k=quad*4+r.
// Wave w's q rows: qt*128 + w*16 + lm. Its diagonal k-tile: t = 2qt + (w>>2);
// low waves (w<4) skip the final tile (wave-uniform; barriers outside).
// NO-MAX softmax; Q pre-scaled; lrow reduced once at the end.
__global__ __launch_bounds__(512) void attn(const unsigned short* __restrict__ Q,
                                            const unsigned short* __restrict__ K,
                                            const unsigned short* __restrict__ Vt,
                                            unsigned short* __restrict__ ctx) {
    constexpr int LKS = 72;
    __shared__ __align__(16) unsigned short Ks[2][64 * LKS];
    __shared__ __align__(16) unsigned short Vts[2][64 * LKS];

    int tid = threadIdx.x, lane = tid & 63, w = tid >> 6;   // w: 0..7
    int lm = lane & 15, quad = lane >> 4;
    int blk = blockIdx.x;
    int bh = blk & 63;
    int qt = 15 - (blk >> 6);   // LPT: heaviest q-tiles dispatch first
    int trips = 2 * qt + 2;
    int tmax = 2 * qt + (w >> 2);  // last trip this wave computes
    const unsigned short* Qg  = Q  + (size_t)bh * 2048 * 64;
    const unsigned short* Kg  = K  + (size_t)bh * 2048 * 64;
    const unsigned short* Vtg = Vt + (size_t)bh * 64 * 2048;

    int qrow = qt * 128 + w * 16 + lm;
    bf16x8 aq0 = *(const bf16x8*)&Qg[qrow * 64 + quad * 8];
    bf16x8 aq1 = *(const bf16x8*)&Qg[qrow * 64 + 32 + quad * 8];

    floatx4 O[4] = {};            // O^T: per dblk, lane holds d=quad*4+r, q=lm
    float lrow = 0.f;

    int r0 = tid >> 3, c0 = (tid & 7) * 8;  // 512 thr -> rows 0..63, 1 uint4 each

    {   // prologue: stage tile 0 into buffer 0
        uint4 k0 = *(const uint4*)&Kg[r0 * 64 + c0];
        uint4 v0 = *(const uint4*)&Vtg[r0 * 2048 + c0];
        *(uint4*)&Ks[0][r0 * LKS + c0]  = k0;
        *(uint4*)&Vts[0][r0 * LKS + c0] = v0;
    }
    __syncthreads();

    for (int t = 0; t < trips; ++t) {
        int cur = t & 1, nxt = cur ^ 1;
        bool pre = (t + 1 < trips);
        uint4 pk, pv;
        if (pre) {  // issue next tile's loads NOW; they complete under compute
            int kb2 = (t + 1) * 64;
            pk = *(const uint4*)&Kg[(kb2 + r0) * 64 + c0];
            pv = *(const uint4*)&Vtg[r0 * 2048 + kb2 + c0];
        }

        if (t <= tmax) {  // wave-uniform; barriers are outside this branch
            const unsigned short* Kc = Ks[cur];
            const unsigned short* Vc = Vts[cur];

            floatx4 s[4];
            for (int n = 0; n < 4; ++n) {
                bf16x8 a0 = *(const bf16x8*)&Kc[(n * 16 + lm) * LKS + quad * 8];
                bf16x8 a1 = *(const bf16x8*)&Kc[(n * 16 + lm) * LKS + 32 + quad * 8];
                floatx4 z = {};
                z = __builtin_amdgcn_mfma_f32_16x16x32_bf16(a0, aq0, z, 0, 0, 0);
                z = __builtin_amdgcn_mfma_f32_16x16x32_bf16(a1, aq1, z, 0, 0, 0);
                s[n] = z;
            }

            bool diag = (t == tmax);
            if (diag) {
                int qr = (w & 3) * 16 + lm;  // q - kb on this wave's diag tile
                for (int n = 0; n < 4; ++n)
                    for (int r = 0; r < 4; ++r)
                        if (n * 16 + quad * 4 + r > qr) s[n][r] = -INFINITY;
            }
            float p[4][4], rs = 0.f;
            for (int n = 0; n < 4; ++n)
                for (int r = 0; r < 4; ++r) {
                    p[n][r] = __builtin_amdgcn_exp2f(s[n][r]);
                    rs += p[n][r];
                }
            lrow += rs;

#ifdef HAVE_MFMA16
            // P^T is ALREADY the 16x16x16 B-frag (B[k=quad*4+i][n=lm]) — no LDS.
            shortx4 pb[4];
            for (int n = 0; n < 4; ++n) {
                union { shortx4 s4; unsigned int w2[2]; } u;
                u.w2[0] = pkbf(p[n][0], p[n][1]);
                u.w2[1] = pkbf(p[n][2], p[n][3]);
                pb[n] = u.s4;
            }
            for (int dblk = 0; dblk < 4; ++dblk)
                for (int n = 0; n < 4; ++n) {
                    shortx4 va = *(const shortx4*)&Vc[(dblk * 16 + lm) * LKS + n * 16 + quad * 4];
                    O[dblk] = __builtin_amdgcn_mfma_f32_16x16x16bf16_1k(va, pb[n], O[dblk], 0, 0, 0);
                }
#else
            unsigned int dw[4][2];
            for (int n = 0; n < 4; ++n) {
                dw[n][0] = pkbf(p[n][0], p[n][1]);
                dw[n][1] = pkbf(p[n][2], p[n][3]);
            }
            bool hiTile = (quad >> 1);
            for (int hh = 0; hh < 2; ++hh) {
                unsigned int bp[4];
                for (int j = 0; j < 4; ++j) {
                    int srcLane = lm + (((quad & 1) * 2 + (j >> 1)) << 4);
                    unsigned int lo = __shfl((int)dw[2 * hh][j & 1], srcLane);
                    unsigned int hi = __shfl((int)dw[2 * hh + 1][j & 1], srcLane);
                    bp[j] = hiTile ? hi : lo;
                }
                bf16x8 bfrag = *(bf16x8*)bp;
                for (int dblk = 0; dblk < 4; ++dblk) {
                    bf16x8 av = *(const bf16x8*)&Vc[(dblk * 16 + lm) * LKS + hh * 32 + quad * 8];
                    O[dblk] = __builtin_amdgcn_mfma_f32_16x16x32_bf16(av, bfrag, O[dblk], 0, 0, 0);
                }
            }
#endif
        }

        if (pre) {  // loads completed under compute; write into other buffer
            *(uint4*)&Ks[nxt][r0 * LKS + c0]  = pk;
            *(uint4*)&Vts[nxt][r0 * LKS + c0] = pv;
        }
        __syncthreads();
    }

    // reduce lrow across the 4 lane-groups holding the same q (once)
    lrow += __shfl_xor(lrow, 16);
    lrow += __shfl_xor(lrow, 32);

    int b = bh >> 4, h = bh & 15;
    int q = qt * 128 + w * 16 + lm;
    float inv = 1.0f / lrow;
    for (int dblk = 0; dblk < 4; ++dblk) {
        *(ushort4*)&ctx[((size_t)(b * 2048 + q)) * 1024 + h * 64 + dblk * 16 + quad * 4] =
            pk4(O[dblk][0] * inv, O[dblk][1] * inv, O[dblk][2] * inv, O[dblk][3] * inv);
    }
}

// ---------------------------------------------------------------- launch
extern "C" void kernel_launch(void* const* d_in, const int* in_sizes, int n_in,
                              void* d_out, int out_size, void* d_ws, size_t ws_size,
                              hipStream_t stream) {
    const float* x   = (const float*)d_in[0];
    const float* Wq  = (const float*)d_in[1];
    const float* Wk  = (const float*)d_in[2];
    const float* Wv  = (const float*)d_in[3];
    const float* Wo  = (const float*)d_in[4];
    const float* bo  = (const float*)d_in[5];
    float* out = (float*)d_out;

    char* ws = (char*)d_ws;
    unsigned short* xb  = (unsigned short*)(ws);               // 16 MB (dead after gemm<0>)
    unsigned short* WT  = (unsigned short*)(ws + 16777216);    // 6 MB
    unsigned short* WoT = (unsigned short*)(ws + 23068672);    // 2 MB
    unsigned short* Qb  = (unsigned short*)(ws + 25165824);    // 16 MB
    unsigned short* Kb  = (unsigned short*)(ws + 41943040);    // 16 MB
    unsigned short* Vtb = (unsigned short*)(ws + 58720256);    // 16 MB (transposed)
    unsigned short* ctx = xb;                                  // alias: xb is dead

    prep<<<12288, 256, 0, stream>>>(x, xb, Wq, Wk, Wv, Wo, WT, WoT);
    gemm_bt<0, 24><<<1536, 256, 0, stream>>>(xb, WT, Qb, Kb, Vtb, nullptr, nullptr);
    attn<<<1024, 512, 0, stream>>>(Qb, Kb, Vtb, ctx);
    gemm_bt<1, 8><<<512, 256, 0, stream>>>(ctx, WoT, nullptr, nullptr, nullptr, bo, out);
}

// Round 4
// 246.975 us; speedup vs baseline: 1.4962x; 1.0294x over previous
//
#include <hip/hip_runtime.h>
#include <hip/hip_bf16.h>
#include <math.h>

// ---------------------------------------------------------------------------
// MultiHeadAttention: x[4,2048,1024] -> causal MHA (16 heads, d=64) -> out proj
// bf16 MFMA everywhere.
// R15: R14 base (verified 254.2us) + minimum 2-phase double-buffer on both
// GEMMs (T3 catalog recipe): STAGE(t+1) issued BEFORE compute(t); the
// __syncthreads() vmcnt(0) drain now waits only the residue of loads that
// ran under ~350cy of ds_read+MFMA. One barrier per K-step (was two).
// LDS 32->64KB per block. No raw barriers / counted vmcnt / phase splits
// (R12/R13 failure modes avoided). attn / prep unchanged.
// ---------------------------------------------------------------------------

typedef __bf16  bf16x8  __attribute__((ext_vector_type(8)));
typedef __bf16  bf16x2  __attribute__((ext_vector_type(2)));
typedef float   floatx4 __attribute__((ext_vector_type(4)));
typedef short   shortx4 __attribute__((ext_vector_type(4)));

#if __has_builtin(__builtin_amdgcn_mfma_f32_16x16x16bf16_1k)
#define HAVE_MFMA16 1
#endif

__device__ __forceinline__ unsigned short f2bf(float f) {
    __hip_bfloat16 h = __float2bfloat16(f);
    return *reinterpret_cast<unsigned short*>(&h);
}

// pack two f32 -> 2xbf16 in one dword (HW packed cvt when available)
__device__ __forceinline__ unsigned int pkbf(float a, float b) {
#if __has_builtin(__builtin_amdgcn_cvt_pk_bf16_f32)
    bf16x2 t = __builtin_amdgcn_cvt_pk_bf16_f32(a, b);
    return __builtin_bit_cast(unsigned int, t);
#else
    return (unsigned int)f2bf(a) | ((unsigned int)f2bf(b) << 16);
#endif
}
__device__ __forceinline__ ushort4 pk4(float a, float b, float c, float d) {
    union { ushort4 u; unsigned int w[2]; } u;
    u.w[0] = pkbf(a, b);
    u.w[1] = pkbf(c, d);
    return u.u;
}

// async global->LDS, 16 B per lane; LDS dest = wave-uniform base + lane*16
__device__ __forceinline__ void gll16(const unsigned short* g, unsigned short* l) {
    __builtin_amdgcn_global_load_lds(
        (const __attribute__((address_space(1))) unsigned int*)g,
        (__attribute__((address_space(3))) unsigned int*)l, 16, 0, 0);
}

// --------------------------------------------- fused convert x + transpose W
__global__ void prep(const float* __restrict__ x, unsigned short* __restrict__ xb,
                     const float* __restrict__ Wq, const float* __restrict__ Wk,
                     const float* __restrict__ Wv, const float* __restrict__ Wo,
                     unsigned short* __restrict__ WT, unsigned short* __restrict__ WoT) {
    __shared__ float tile[32][33];
    int bid = blockIdx.x, tid = threadIdx.x;
    if (bid < 8192) {
        int i = (bid * 256 + tid) * 4;
        float4 v = *(const float4*)(x + i);
        *(ushort4*)(xb + i) = pk4(v.x, v.y, v.z, v.w);
        return;
    }
    int id = bid - 8192;
    int mat = id >> 10, rem = id & 1023;
    const float* src = (mat == 0) ? Wq : (mat == 1) ? Wk : (mat == 2) ? Wv : Wo;
    unsigned short* dst = (mat < 3) ? WT : WoT;
    int nbase = (mat < 3) ? mat * 1024 : 0;
    int kt = (rem & 31) * 32, nt = (rem >> 5) * 32;
    int tx = tid & 31, ty = tid >> 5;  // 32 x 8
    for (int j = 0; j < 32; j += 8)
        tile[ty + j][tx] = src[(kt + ty + j) * 1024 + nt + tx];
    __syncthreads();
    for (int j = 0; j < 32; j += 8) {
        int n = nt + ty + j;
        dst[(nbase + n) * 1024 + kt + tx] = f2bf(tile[tx][ty + j]);
    }
}

// ---------------------------------------------------------------- GEMM B^T
// C[M,N] = A[M,1024] @ B^T (B stored [N][1024]). 128x128 tile, BK=64.
// Double-buffered gll16 staging (stage t+1 before compute t); XOR swizzle
// (0 bank conflicts). One __syncthreads per K-step; its vmcnt(0) waits only
// the residue of loads issued ~350cy earlier.
// Flat grid + XCD-chunked bijective swizzle (T1, neutral-but-harmless here).
// Orientation: swapped (C^T) for Q/K columns (n0<2048) and all of EPI1.
template <int EPI, int NBLK>
__global__ __launch_bounds__(256) void gemm_bt(const unsigned short* __restrict__ A,
                                               const unsigned short* __restrict__ B,
                                               unsigned short* __restrict__ Qo,
                                               unsigned short* __restrict__ Ko,
                                               unsigned short* __restrict__ Vo,
                                               const float* __restrict__ bias,
                                               float* __restrict__ Out) {
    __shared__ __align__(16) unsigned short As[2][128 * 64];
    __shared__ __align__(16) unsigned short Bs[2][128 * 64];

    int tid = threadIdx.x;
    int lane = tid & 63, w = tid >> 6;
    int wm = w >> 1, wn = w & 1;
    int lm = lane & 15, quad = lane >> 4;
    // T1 swizzle: bid&7 -> XCD chunk; within chunk m-fastest over the 8-band.
    int bid = blockIdx.x;
    int xcd = bid & 7, ic = bid >> 3;
    int bm = xcd * 8 + (ic & 7), bn = ic >> 3;  // bn in [0, NBLK)
    int m0 = bm * 128, n0 = bn * 128;
    bool sw = (EPI == 1) || (n0 < 2048);  // block-uniform orientation

    // stage one full 128x64 K-tile of A and B into buffer `buf`
    auto STAGE = [&](int buf, int kb) {
#pragma unroll
        for (int p = 0; p < 4; ++p) {
            int id = p * 256 + tid;
            int row = id >> 3;
            int cbs = ((id & 7) ^ (row & 7)) * 8;  // XOR-swizzled source unit
            int lbase = (p * 256 + w * 64) * 8;    // wave-uniform; HW adds lane*16B
            gll16(&A[(m0 + row) * 1024 + kb + cbs], &As[buf][lbase]);
            gll16(&B[(n0 + row) * 1024 + kb + cbs], &Bs[buf][lbase]);
        }
    };

    floatx4 acc[4][4] = {};

    STAGE(0, 0);
    __syncthreads();   // compiler drains vmcnt(0): tile 0 resident

#pragma unroll 2
    for (int t = 0; t < 16; ++t) {
        if (t < 15) STAGE((t + 1) & 1, (t + 1) * 64);  // loads fly under compute
        const unsigned short* Ac = &As[t & 1][0];
        const unsigned short* Bc = &Bs[t & 1][0];

        bf16x8 af[2][4], bf[2][4];
        for (int ks = 0; ks < 2; ++ks)
            for (int i = 0; i < 4; ++i) {
                int pu = (((ks * 4 + quad) ^ (lm & 7))) * 8;  // swizzled unit
                af[ks][i] = *(const bf16x8*)&Ac[(wm * 64 + i * 16 + lm) * 64 + pu];
                bf[ks][i] = *(const bf16x8*)&Bc[(wn * 64 + i * 16 + lm) * 64 + pu];
            }
        if (sw) {
            for (int mi = 0; mi < 4; ++mi)
                for (int ni = 0; ni < 4; ++ni) {
                    acc[mi][ni] = __builtin_amdgcn_mfma_f32_16x16x32_bf16(bf[0][ni], af[0][mi], acc[mi][ni], 0, 0, 0);
                    acc[mi][ni] = __builtin_amdgcn_mfma_f32_16x16x32_bf16(bf[1][ni], af[1][mi], acc[mi][ni], 0, 0, 0);
                }
        } else {
            for (int mi = 0; mi < 4; ++mi)
                for (int ni = 0; ni < 4; ++ni) {
                    acc[mi][ni] = __builtin_amdgcn_mfma_f32_16x16x32_bf16(af[0][mi], bf[0][ni], acc[mi][ni], 0, 0, 0);
                    acc[mi][ni] = __builtin_amdgcn_mfma_f32_16x16x32_bf16(af[1][mi], bf[1][ni], acc[mi][ni], 0, 0, 0);
                }
        }
        // waits lgkmcnt(0) (ds_reads of buf[t&1] done -> safe to restage it
        // next iter) AND vmcnt(0) (buf[(t+1)&1] writes landed -> safe to read).
        __syncthreads();
    }

    if constexpr (EPI == 0) {
        if (sw) {
            // C^T layout: lane owns seq s (col=lm) and 4 consecutive out-cols.
            bool isQ = (n0 < 1024);
            unsigned short* dst = isQ ? Qo : Ko;
            float qs = isQ ? 0.1803368801f : 1.0f;  // 1/8 * log2(e)
            for (int mi = 0; mi < 4; ++mi) {
                int s = m0 + wm * 64 + mi * 16 + lm;
                int bb = s >> 11, sl = s & 2047;
                for (int ni = 0; ni < 4; ++ni) {
                    int gcol0 = n0 + wn * 64 + ni * 16 + quad * 4;
                    int h = (gcol0 & 1023) >> 6, d0 = gcol0 & 63;
                    *(ushort4*)&dst[(((size_t)(bb * 16 + h) * 2048) + sl) * 64 + d0] =
                        pk4(acc[mi][ni][0] * qs, acc[mi][ni][1] * qs,
                            acc[mi][ni][2] * qs, acc[mi][ni][3] * qs);
                }
            }
        } else {
            // V columns, normal layout: packed along seq for V^T [bh][d][2048].
            for (int mi = 0; mi < 4; ++mi) {
                int grow0 = m0 + wm * 64 + mi * 16 + quad * 4;
                int bb = grow0 >> 11, sl = grow0 & 2047;
                for (int ni = 0; ni < 4; ++ni) {
                    int gcol = n0 + wn * 64 + ni * 16 + lm;
                    int hn = gcol & 1023;
                    int h = hn >> 6, d = hn & 63;
                    *(ushort4*)&Vo[((size_t)(bb * 16 + h) * 64 + d) * 2048 + sl] =
                        pk4(acc[mi][ni][0], acc[mi][ni][1], acc[mi][ni][2], acc[mi][ni][3]);
                }
            }
        }
    } else {
        // out-proj: C^T layout -> float4 stores + float4 bias loads
        for (int mi = 0; mi < 4; ++mi) {
            int s = m0 + wm * 64 + mi * 16 + lm;
            for (int ni = 0; ni < 4; ++ni) {
                int gcol0 = n0 + wn * 64 + ni * 16 + quad * 4;
                float4 bv = *(const float4*)&bias[gcol0];
                float4 o;
                o.x = acc[mi][ni][0] + bv.x; o.y = acc[mi][ni][1] + bv.y;
                o.z = acc[mi][ni][2] + bv.z; o.w = acc[mi][ni][3] + bv.w;
                *(float4*)&Out[(size_t)s * 1024 + gcol0] = o;
            }
        }
    }
}

// ------------------------------------------------------------- attention
// Flat grid 1024 = (qt heavy-first, 16 tiles of 128 q) x 64 bh.
// 512 thr = 8 waves x 16 q-rows. KB=64. S^T orientation: q=lm, k=quad*4+r.
// Wave w's q rows: qt*128 + w*16 + lm. Its diagonal k-tile: t = 2qt + (w>>2);
// low waves (w<4) skip the final tile (wave-uniform; barriers outside).
// NO-MAX softmax; Q pre-scaled; lrow reduced once at the end.
__global__ __launch_bounds__(512) void attn(const unsigned short* __restrict__ Q,
                                            const unsigned short* __restrict__ K,
                                            const unsigned short* __restrict__ Vt,
                                            unsigned short* __restrict__ ctx) {
    constexpr int LKS = 72;
    __shared__ __align__(16) unsigned short Ks[2][64 * LKS];
    __shared__ __align__(16) unsigned short Vts[2][64 * LKS];

    int tid = threadIdx.x, lane = tid & 63, w = tid >> 6;   // w: 0..7
    int lm = lane & 15, quad = lane >> 4;
    int blk = blockIdx.x;
    int bh = blk & 63;
    int qt = 15 - (blk >> 6);   // LPT: heaviest q-tiles dispatch first
    int trips = 2 * qt + 2;
    int tmax = 2 * qt + (w >> 2);  // last trip this wave computes
    const unsigned short* Qg  = Q  + (size_t)bh * 2048 * 64;
    const unsigned short* Kg  = K  + (size_t)bh * 2048 * 64;
    const unsigned short* Vtg = Vt + (size_t)bh * 64 * 2048;

    int qrow = qt * 128 + w * 16 + lm;
    bf16x8 aq0 = *(const bf16x8*)&Qg[qrow * 64 + quad * 8];
    bf16x8 aq1 = *(const bf16x8*)&Qg[qrow * 64 + 32 + quad * 8];

    floatx4 O[4] = {};            // O^T: per dblk, lane holds d=quad*4+r, q=lm
    float lrow = 0.f;

    int r0 = tid >> 3, c0 = (tid & 7) * 8;  // 512 thr -> rows 0..63, 1 uint4 each

    {   // prologue: stage tile 0 into buffer 0
        uint4 k0 = *(const uint4*)&Kg[r0 * 64 + c0];
        uint4 v0 = *(const uint4*)&Vtg[r0 * 2048 + c0];
        *(uint4*)&Ks[0][r0 * LKS + c0]  = k0;
        *(uint4*)&Vts[0][r0 * LKS + c0] = v0;
    }
    __syncthreads();

    for (int t = 0; t < trips; ++t) {
        int cur = t & 1, nxt = cur ^ 1;
        bool pre = (t + 1 < trips);
        uint4 pk, pv;
        if (pre) {  // issue next tile's loads NOW; they complete under compute
            int kb2 = (t + 1) * 64;
            pk = *(const uint4*)&Kg[(kb2 + r0) * 64 + c0];
            pv = *(const uint4*)&Vtg[r0 * 2048 + kb2 + c0];
        }

        if (t <= tmax) {  // wave-uniform; barriers are outside this branch
            const unsigned short* Kc = Ks[cur];
            const unsigned short* Vc = Vts[cur];

            floatx4 s[4];
            for (int n = 0; n < 4; ++n) {
                bf16x8 a0 = *(const bf16x8*)&Kc[(n * 16 + lm) * LKS + quad * 8];
                bf16x8 a1 = *(const bf16x8*)&Kc[(n * 16 + lm) * LKS + 32 + quad * 8];
                floatx4 z = {};
                z = __builtin_amdgcn_mfma_f32_16x16x32_bf16(a0, aq0, z, 0, 0, 0);
                z = __builtin_amdgcn_mfma_f32_16x16x32_bf16(a1, aq1, z, 0, 0, 0);
                s[n] = z;
            }

            bool diag = (t == tmax);
            if (diag) {
                int qr = (w & 3) * 16 + lm;  // q - kb on this wave's diag tile
                for (int n = 0; n < 4; ++n)
                    for (int r = 0; r < 4; ++r)
                        if (n * 16 + quad * 4 + r > qr) s[n][r] = -INFINITY;
            }
            float p[4][4], rs = 0.f;
            for (int n = 0; n < 4; ++n)
                for (int r = 0; r < 4; ++r) {
                    p[n][r] = __builtin_amdgcn_exp2f(s[n][r]);
                    rs += p[n][r];
                }
            lrow += rs;

#ifdef HAVE_MFMA16
            // P^T is ALREADY the 16x16x16 B-frag (B[k=quad*4+i][n=lm]) — no LDS.
            shortx4 pb[4];
            for (int n = 0; n < 4; ++n) {
                union { shortx4 s4; unsigned int w2[2]; } u;
                u.w2[0] = pkbf(p[n][0], p[n][1]);
                u.w2[1] = pkbf(p[n][2], p[n][3]);
                pb[n] = u.s4;
            }
            for (int dblk = 0; dblk < 4; ++dblk)
                for (int n = 0; n < 4; ++n) {
                    shortx4 va = *(const shortx4*)&Vc[(dblk * 16 + lm) * LKS + n * 16 + quad * 4];
                    O[dblk] = __builtin_amdgcn_mfma_f32_16x16x16bf16_1k(va, pb[n], O[dblk], 0, 0, 0);
                }
#else
            unsigned int dw[4][2];
            for (int n = 0; n < 4; ++n) {
                dw[n][0] = pkbf(p[n][0], p[n][1]);
                dw[n][1] = pkbf(p[n][2], p[n][3]);
            }
            bool hiTile = (quad >> 1);
            for (int hh = 0; hh < 2; ++hh) {
                unsigned int bp[4];
                for (int j = 0; j < 4; ++j) {
                    int srcLane = lm + (((quad & 1) * 2 + (j >> 1)) << 4);
                    unsigned int lo = __shfl((int)dw[2 * hh][j & 1], srcLane);
                    unsigned int hi = __shfl((int)dw[2 * hh + 1][j & 1], srcLane);
                    bp[j] = hiTile ? hi : lo;
                }
                bf16x8 bfrag = *(bf16x8*)bp;
                for (int dblk = 0; dblk < 4; ++dblk) {
                    bf16x8 av = *(const bf16x8*)&Vc[(dblk * 16 + lm) * LKS + hh * 32 + quad * 8];
                    O[dblk] = __builtin_amdgcn_mfma_f32_16x16x32_bf16(av, bfrag, O[dblk], 0, 0, 0);
                }
            }
#endif
        }

        if (pre) {  // loads completed under compute; write into other buffer
            *(uint4*)&Ks[nxt][r0 * LKS + c0]  = pk;
            *(uint4*)&Vts[nxt][r0 * LKS + c0] = pv;
        }
        __syncthreads();
    }

    // reduce lrow across the 4 lane-groups holding the same q (once)
    lrow += __shfl_xor(lrow, 16);
    lrow += __shfl_xor(lrow, 32);

    int b = bh >> 4, h = bh & 15;
    int q = qt * 128 + w * 16 + lm;
    float inv = 1.0f / lrow;
    for (int dblk = 0; dblk < 4; ++dblk) {
        *(ushort4*)&ctx[((size_t)(b * 2048 + q)) * 1024 + h * 64 + dblk * 16 + quad * 4] =
            pk4(O[dblk][0] * inv, O[dblk][1] * inv, O[dblk][2] * inv, O[dblk][3] * inv);
    }
}

// ---------------------------------------------------------------- launch
extern "C" void kernel_launch(void* const* d_in, const int* in_sizes, int n_in,
                              void* d_out, int out_size, void* d_ws, size_t ws_size,
                              hipStream_t stream) {
    const float* x   = (const float*)d_in[0];
    const float* Wq  = (const float*)d_in[1];
    const float* Wk  = (const float*)d_in[2];
    const float* Wv  = (const float*)d_in[3];
    const float* Wo  = (const float*)d_in[4];
    const float* bo  = (const float*)d_in[5];
    float* out = (float*)d_out;

    char* ws = (char*)d_ws;
    unsigned short* xb  = (unsigned short*)(ws);               // 16 MB (dead after gemm<0>)
    unsigned short* WT  = (unsigned short*)(ws + 16777216);    // 6 MB
    unsigned short* WoT = (unsigned short*)(ws + 23068672);    // 2 MB
    unsigned short* Qb  = (unsigned short*)(ws + 25165824);    // 16 MB
    unsigned short* Kb  = (unsigned short*)(ws + 41943040);    // 16 MB
    unsigned short* Vtb = (unsigned short*)(ws + 58720256);    // 16 MB (transposed)
    unsigned short* ctx = xb;                                  // alias: xb is dead

    prep<<<12288, 256, 0, stream>>>(x, xb, Wq, Wk, Wv, Wo, WT, WoT);
    gemm_bt<0, 24><<<1536, 256, 0, stream>>>(xb, WT, Qb, Kb, Vtb, nullptr, nullptr);
    attn<<<1024, 512, 0, stream>>>(Qb, Kb, Vtb, ctx);
    gemm_bt<1, 8><<<512, 256, 0, stream>>>(ctx, WoT, nullptr, nullptr, nullptr, bo, out);
}

// Round 5
// 233.454 us; speedup vs baseline: 1.5828x; 1.0579x over previous
//
#include <hip/hip_runtime.h>
#include <hip/hip_bf16.h>
#include <math.h>

// ---------------------------------------------------------------------------
// MultiHeadAttention: x[4,2048,1024] -> causal MHA (16 heads, d=64) -> out proj
// bf16 MFMA everywhere.
// R16: R15 base (verified 247.0us) + attn PV bank-conflict fix: the 16
// ds_read_b64 va reads (8B-aligned -> even banks only, 4 lanes/bank, 13M
// conflicts/dispatch) are replaced by 8 ds_read_b128 via a k-window
// permutation sigma_n(m) = 32(n>>1) + 4(n&1) + 8(m>>2) + (m&3):
// - K staged into LDS rows pre-permuted (bijective krho, QK read code
//   unchanged; staging stays conflict-free b128),
// - each b128 V read = lo/hi shortx4 fragments for windows 2n1 / 2n1+1,
// - causal mask uses the permuted in-tile k. V staging & arithmetic
//   unchanged (summation order only). GEMMs / prep unchanged from R15.
// ---------------------------------------------------------------------------

typedef __bf16  bf16x8  __attribute__((ext_vector_type(8)));
typedef __bf16  bf16x2  __attribute__((ext_vector_type(2)));
typedef float   floatx4 __attribute__((ext_vector_type(4)));
typedef short   shortx4 __attribute__((ext_vector_type(4)));

#if __has_builtin(__builtin_amdgcn_mfma_f32_16x16x16bf16_1k)
#define HAVE_MFMA16 1
#endif

__device__ __forceinline__ unsigned short f2bf(float f) {
    __hip_bfloat16 h = __float2bfloat16(f);
    return *reinterpret_cast<unsigned short*>(&h);
}

// pack two f32 -> 2xbf16 in one dword (HW packed cvt when available)
__device__ __forceinline__ unsigned int pkbf(float a, float b) {
#if __has_builtin(__builtin_amdgcn_cvt_pk_bf16_f32)
    bf16x2 t = __builtin_amdgcn_cvt_pk_bf16_f32(a, b);
    return __builtin_bit_cast(unsigned int, t);
#else
    return (unsigned int)f2bf(a) | ((unsigned int)f2bf(b) << 16);
#endif
}
__device__ __forceinline__ ushort4 pk4(float a, float b, float c, float d) {
    union { ushort4 u; unsigned int w[2]; } u;
    u.w[0] = pkbf(a, b);
    u.w[1] = pkbf(c, d);
    return u.u;
}

// async global->LDS, 16 B per lane; LDS dest = wave-uniform base + lane*16
__device__ __forceinline__ void gll16(const unsigned short* g, unsigned short* l) {
    __builtin_amdgcn_global_load_lds(
        (const __attribute__((address_space(1))) unsigned int*)g,
        (__attribute__((address_space(3))) unsigned int*)l, 16, 0, 0);
}

// K LDS row permutation (MFMA16 path): lds row j holds global k-row pi(j),
// pi(j) = 32*(j>>5) + 4*((j>>4)&1) + 8*((j&15)>>2) + (j&3).
// krho = pi^{-1}: staging writes global row r into lds row krho(r).
// Verified bijective: pi(krho(r)) == r.
#ifdef HAVE_MFMA16
__device__ __forceinline__ int krho(int r) {
    return (r & 0x20) | ((r & 4) << 2) | ((r & 0x18) >> 1) | (r & 3);
}
#else
__device__ __forceinline__ int krho(int r) { return r; }
#endif

// --------------------------------------------- fused convert x + transpose W
__global__ void prep(const float* __restrict__ x, unsigned short* __restrict__ xb,
                     const float* __restrict__ Wq, const float* __restrict__ Wk,
                     const float* __restrict__ Wv, const float* __restrict__ Wo,
                     unsigned short* __restrict__ WT, unsigned short* __restrict__ WoT) {
    __shared__ float tile[32][33];
    int bid = blockIdx.x, tid = threadIdx.x;
    if (bid < 8192) {
        int i = (bid * 256 + tid) * 4;
        float4 v = *(const float4*)(x + i);
        *(ushort4*)(xb + i) = pk4(v.x, v.y, v.z, v.w);
        return;
    }
    int id = bid - 8192;
    int mat = id >> 10, rem = id & 1023;
    const float* src = (mat == 0) ? Wq : (mat == 1) ? Wk : (mat == 2) ? Wv : Wo;
    unsigned short* dst = (mat < 3) ? WT : WoT;
    int nbase = (mat < 3) ? mat * 1024 : 0;
    int kt = (rem & 31) * 32, nt = (rem >> 5) * 32;
    int tx = tid & 31, ty = tid >> 5;  // 32 x 8
    for (int j = 0; j < 32; j += 8)
        tile[ty + j][tx] = src[(kt + ty + j) * 1024 + nt + tx];
    __syncthreads();
    for (int j = 0; j < 32; j += 8) {
        int n = nt + ty + j;
        dst[(nbase + n) * 1024 + kt + tx] = f2bf(tile[tx][ty + j]);
    }
}

// ---------------------------------------------------------------- GEMM B^T
// C[M,N] = A[M,1024] @ B^T (B stored [N][1024]). 128x128 tile, BK=64.
// Double-buffered gll16 staging (stage t+1 before compute t); XOR swizzle
// (0 bank conflicts). One __syncthreads per K-step.
// Flat grid + XCD-chunked bijective swizzle (T1, neutral-but-harmless here).
// Orientation: swapped (C^T) for Q/K columns (n0<2048) and all of EPI1.
template <int EPI, int NBLK>
__global__ __launch_bounds__(256) void gemm_bt(const unsigned short* __restrict__ A,
                                               const unsigned short* __restrict__ B,
                                               unsigned short* __restrict__ Qo,
                                               unsigned short* __restrict__ Ko,
                                               unsigned short* __restrict__ Vo,
                                               const float* __restrict__ bias,
                                               float* __restrict__ Out) {
    __shared__ __align__(16) unsigned short As[2][128 * 64];
    __shared__ __align__(16) unsigned short Bs[2][128 * 64];

    int tid = threadIdx.x;
    int lane = tid & 63, w = tid >> 6;
    int wm = w >> 1, wn = w & 1;
    int lm = lane & 15, quad = lane >> 4;
    // T1 swizzle: bid&7 -> XCD chunk; within chunk m-fastest over the 8-band.
    int bid = blockIdx.x;
    int xcd = bid & 7, ic = bid >> 3;
    int bm = xcd * 8 + (ic & 7), bn = ic >> 3;  // bn in [0, NBLK)
    int m0 = bm * 128, n0 = bn * 128;
    bool sw = (EPI == 1) || (n0 < 2048);  // block-uniform orientation

    // stage one full 128x64 K-tile of A and B into buffer `buf`
    auto STAGE = [&](int buf, int kb) {
#pragma unroll
        for (int p = 0; p < 4; ++p) {
            int id = p * 256 + tid;
            int row = id >> 3;
            int cbs = ((id & 7) ^ (row & 7)) * 8;  // XOR-swizzled source unit
            int lbase = (p * 256 + w * 64) * 8;    // wave-uniform; HW adds lane*16B
            gll16(&A[(m0 + row) * 1024 + kb + cbs], &As[buf][lbase]);
            gll16(&B[(n0 + row) * 1024 + kb + cbs], &Bs[buf][lbase]);
        }
    };

    floatx4 acc[4][4] = {};

    STAGE(0, 0);
    __syncthreads();   // compiler drains vmcnt(0): tile 0 resident

#pragma unroll 2
    for (int t = 0; t < 16; ++t) {
        if (t < 15) STAGE((t + 1) & 1, (t + 1) * 64);  // loads fly under compute
        const unsigned short* Ac = &As[t & 1][0];
        const unsigned short* Bc = &Bs[t & 1][0];

        bf16x8 af[2][4], bf[2][4];
        for (int ks = 0; ks < 2; ++ks)
            for (int i = 0; i < 4; ++i) {
                int pu = (((ks * 4 + quad) ^ (lm & 7))) * 8;  // swizzled unit
                af[ks][i] = *(const bf16x8*)&Ac[(wm * 64 + i * 16 + lm) * 64 + pu];
                bf[ks][i] = *(const bf16x8*)&Bc[(wn * 64 + i * 16 + lm) * 64 + pu];
            }
        if (sw) {
            for (int mi = 0; mi < 4; ++mi)
                for (int ni = 0; ni < 4; ++ni) {
                    acc[mi][ni] = __builtin_amdgcn_mfma_f32_16x16x32_bf16(bf[0][ni], af[0][mi], acc[mi][ni], 0, 0, 0);
                    acc[mi][ni] = __builtin_amdgcn_mfma_f32_16x16x32_bf16(bf[1][ni], af[1][mi], acc[mi][ni], 0, 0, 0);
                }
        } else {
            for (int mi = 0; mi < 4; ++mi)
                for (int ni = 0; ni < 4; ++ni) {
                    acc[mi][ni] = __builtin_amdgcn_mfma_f32_16x16x32_bf16(af[0][mi], bf[0][ni], acc[mi][ni], 0, 0, 0);
                    acc[mi][ni] = __builtin_amdgcn_mfma_f32_16x16x32_bf16(af[1][mi], bf[1][ni], acc[mi][ni], 0, 0, 0);
                }
        }
        // waits lgkmcnt(0) (ds_reads of buf[t&1] done -> safe to restage it
        // next iter) AND vmcnt(0) (buf[(t+1)&1] writes landed -> safe to read).
        __syncthreads();
    }

    if constexpr (EPI == 0) {
        if (sw) {
            // C^T layout: lane owns seq s (col=lm) and 4 consecutive out-cols.
            bool isQ = (n0 < 1024);
            unsigned short* dst = isQ ? Qo : Ko;
            float qs = isQ ? 0.1803368801f : 1.0f;  // 1/8 * log2(e)
            for (int mi = 0; mi < 4; ++mi) {
                int s = m0 + wm * 64 + mi * 16 + lm;
                int bb = s >> 11, sl = s & 2047;
                for (int ni = 0; ni < 4; ++ni) {
                    int gcol0 = n0 + wn * 64 + ni * 16 + quad * 4;
                    int h = (gcol0 & 1023) >> 6, d0 = gcol0 & 63;
                    *(ushort4*)&dst[(((size_t)(bb * 16 + h) * 2048) + sl) * 64 + d0] =
                        pk4(acc[mi][ni][0] * qs, acc[mi][ni][1] * qs,
                            acc[mi][ni][2] * qs, acc[mi][ni][3] * qs);
                }
            }
        } else {
            // V columns, normal layout: packed along seq for V^T [bh][d][2048].
            for (int mi = 0; mi < 4; ++mi) {
                int grow0 = m0 + wm * 64 + mi * 16 + quad * 4;
                int bb = grow0 >> 11, sl = grow0 & 2047;
                for (int ni = 0; ni < 4; ++ni) {
                    int gcol = n0 + wn * 64 + ni * 16 + lm;
                    int hn = gcol & 1023;
                    int h = hn >> 6, d = hn & 63;
                    *(ushort4*)&Vo[((size_t)(bb * 16 + h) * 64 + d) * 2048 + sl] =
                        pk4(acc[mi][ni][0], acc[mi][ni][1], acc[mi][ni][2], acc[mi][ni][3]);
                }
            }
        }
    } else {
        // out-proj: C^T layout -> float4 stores + float4 bias loads
        for (int mi = 0; mi < 4; ++mi) {
            int s = m0 + wm * 64 + mi * 16 + lm;
            for (int ni = 0; ni < 4; ++ni) {
                int gcol0 = n0 + wn * 64 + ni * 16 + quad * 4;
                float4 bv = *(const float4*)&bias[gcol0];
                float4 o;
                o.x = acc[mi][ni][0] + bv.x; o.y = acc[mi][ni][1] + bv.y;
                o.z = acc[mi][ni][2] + bv.z; o.w = acc[mi][ni][3] + bv.w;
                *(float4*)&Out[(size_t)s * 1024 + gcol0] = o;
            }
        }
    }
}

// ------------------------------------------------------------- attention
// Flat grid 1024 = (qt heavy-first, 16 tiles of 128 q) x 64 bh.
// 512 thr = 8 waves x 16 q-rows. KB=64. S^T orientation: q=lm.
// MFMA16 path: K lds rows permuted by krho so S^T rows follow
// sigma_n(m)=32(n>>1)+4(n&1)+8(m>>2)+(m&3); PV V-reads are then b128
// (lo/hi halves = windows 2n1 / 2n1+1) -> conflict-free LDS.
// NO-MAX softmax; Q pre-scaled; lrow reduced once at the end.
__global__ __launch_bounds__(512) void attn(const unsigned short* __restrict__ Q,
                                            const unsigned short* __restrict__ K,
                                            const unsigned short* __restrict__ Vt,
                                            unsigned short* __restrict__ ctx) {
    constexpr int LKS = 72;
    __shared__ __align__(16) unsigned short Ks[2][64 * LKS];
    __shared__ __align__(16) unsigned short Vts[2][64 * LKS];

    int tid = threadIdx.x, lane = tid & 63, w = tid >> 6;   // w: 0..7
    int lm = lane & 15, quad = lane >> 4;
    int blk = blockIdx.x;
    int bh = blk & 63;
    int qt = 15 - (blk >> 6);   // LPT: heaviest q-tiles dispatch first
    int trips = 2 * qt + 2;
    int tmax = 2 * qt + (w >> 2);  // last trip this wave computes
    const unsigned short* Qg  = Q  + (size_t)bh * 2048 * 64;
    const unsigned short* Kg  = K  + (size_t)bh * 2048 * 64;
    const unsigned short* Vtg = Vt + (size_t)bh * 64 * 2048;

    int qrow = qt * 128 + w * 16 + lm;
    bf16x8 aq0 = *(const bf16x8*)&Qg[qrow * 64 + quad * 8];
    bf16x8 aq1 = *(const bf16x8*)&Qg[qrow * 64 + 32 + quad * 8];

    floatx4 O[4] = {};            // O^T: per dblk, lane holds d=quad*4+r, q=lm
    float lrow = 0.f;

    int r0 = tid >> 3, c0 = (tid & 7) * 8;  // 512 thr -> rows 0..63, 1 uint4 each
    int rK = krho(r0);                      // permuted K lds row (identity w/o MFMA16)

    {   // prologue: stage tile 0 into buffer 0
        uint4 k0 = *(const uint4*)&Kg[r0 * 64 + c0];
        uint4 v0 = *(const uint4*)&Vtg[r0 * 2048 + c0];
        *(uint4*)&Ks[0][rK * LKS + c0]  = k0;
        *(uint4*)&Vts[0][r0 * LKS + c0] = v0;
    }
    __syncthreads();

    for (int t = 0; t < trips; ++t) {
        int cur = t & 1, nxt = cur ^ 1;
        bool pre = (t + 1 < trips);
        uint4 pk, pv;
        if (pre) {  // issue next tile's loads NOW; they complete under compute
            int kb2 = (t + 1) * 64;
            pk = *(const uint4*)&Kg[(kb2 + r0) * 64 + c0];
            pv = *(const uint4*)&Vtg[r0 * 2048 + kb2 + c0];
        }

        if (t <= tmax) {  // wave-uniform; barriers are outside this branch
            const unsigned short* Kc = Ks[cur];
            const unsigned short* Vc = Vts[cur];

            floatx4 s[4];
            for (int n = 0; n < 4; ++n) {
                bf16x8 a0 = *(const bf16x8*)&Kc[(n * 16 + lm) * LKS + quad * 8];
                bf16x8 a1 = *(const bf16x8*)&Kc[(n * 16 + lm) * LKS + 32 + quad * 8];
                floatx4 z = {};
                z = __builtin_amdgcn_mfma_f32_16x16x32_bf16(a0, aq0, z, 0, 0, 0);
                z = __builtin_amdgcn_mfma_f32_16x16x32_bf16(a1, aq1, z, 0, 0, 0);
                s[n] = z;
            }

            bool diag = (t == tmax);
            if (diag) {
                int qr = (w & 3) * 16 + lm;  // q - kb on this wave's diag tile
                for (int n = 0; n < 4; ++n)
                    for (int r = 0; r < 4; ++r) {
#ifdef HAVE_MFMA16
                        int kin = (n >> 1) * 32 + (n & 1) * 4 + quad * 8 + r;
#else
                        int kin = n * 16 + quad * 4 + r;
#endif
                        if (kin > qr) s[n][r] = -INFINITY;
                    }
            }
            float p[4][4], rs = 0.f;
            for (int n = 0; n < 4; ++n)
                for (int r = 0; r < 4; ++r) {
                    p[n][r] = __builtin_amdgcn_exp2f(s[n][r]);
                    rs += p[n][r];
                }
            lrow += rs;

#ifdef HAVE_MFMA16
            // P^T is the 16x16x16 B-frag for window sigma_n; V read as b128:
            // lo/hi shortx4 halves feed windows 2n1 / 2n1+1. Conflict-free.
            shortx4 pb[4];
            for (int n = 0; n < 4; ++n) {
                union { shortx4 s4; unsigned int w2[2]; } u;
                u.w2[0] = pkbf(p[n][0], p[n][1]);
                u.w2[1] = pkbf(p[n][2], p[n][3]);
                pb[n] = u.s4;
            }
            for (int dblk = 0; dblk < 4; ++dblk)
                for (int n1 = 0; n1 < 2; ++n1) {
                    union { bf16x8 v; shortx4 h[2]; } u;
                    u.v = *(const bf16x8*)&Vc[(dblk * 16 + lm) * LKS + n1 * 32 + quad * 8];
                    O[dblk] = __builtin_amdgcn_mfma_f32_16x16x16bf16_1k(u.h[0], pb[2 * n1], O[dblk], 0, 0, 0);
                    O[dblk] = __builtin_amdgcn_mfma_f32_16x16x16bf16_1k(u.h[1], pb[2 * n1 + 1], O[dblk], 0, 0, 0);
                }
#else
            unsigned int dw[4][2];
            for (int n = 0; n < 4; ++n) {
                dw[n][0] = pkbf(p[n][0], p[n][1]);
                dw[n][1] = pkbf(p[n][2], p[n][3]);
            }
            bool hiTile = (quad >> 1);
            for (int hh = 0; hh < 2; ++hh) {
                unsigned int bp[4];
                for (int j = 0; j < 4; ++j) {
                    int srcLane = lm + (((quad & 1) * 2 + (j >> 1)) << 4);
                    unsigned int lo = __shfl((int)dw[2 * hh][j & 1], srcLane);
                    unsigned int hi = __shfl((int)dw[2 * hh + 1][j & 1], srcLane);
                    bp[j] = hiTile ? hi : lo;
                }
                bf16x8 bfrag = *(bf16x8*)bp;
                for (int dblk = 0; dblk < 4; ++dblk) {
                    bf16x8 av = *(const bf16x8*)&Vc[(dblk * 16 + lm) * LKS + hh * 32 + quad * 8];
                    O[dblk] = __builtin_amdgcn_mfma_f32_16x16x32_bf16(av, bfrag, O[dblk], 0, 0, 0);
                }
            }
#endif
        }

        if (pre) {  // loads completed under compute; write into other buffer
            *(uint4*)&Ks[nxt][rK * LKS + c0]  = pk;
            *(uint4*)&Vts[nxt][r0 * LKS + c0] = pv;
        }
        __syncthreads();
    }

    // reduce lrow across the 4 lane-groups holding the same q (once)
    lrow += __shfl_xor(lrow, 16);
    lrow += __shfl_xor(lrow, 32);

    int b = bh >> 4, h = bh & 15;
    int q = qt * 128 + w * 16 + lm;
    float inv = 1.0f / lrow;
    for (int dblk = 0; dblk < 4; ++dblk) {
        *(ushort4*)&ctx[((size_t)(b * 2048 + q)) * 1024 + h * 64 + dblk * 16 + quad * 4] =
            pk4(O[dblk][0] * inv, O[dblk][1] * inv, O[dblk][2] * inv, O[dblk][3] * inv);
    }
}

// ---------------------------------------------------------------- launch
extern "C" void kernel_launch(void* const* d_in, const int* in_sizes, int n_in,
                              void* d_out, int out_size, void* d_ws, size_t ws_size,
                              hipStream_t stream) {
    const float* x   = (const float*)d_in[0];
    const float* Wq  = (const float*)d_in[1];
    const float* Wk  = (const float*)d_in[2];
    const float* Wv  = (const float*)d_in[3];
    const float* Wo  = (const float*)d_in[4];
    const float* bo  = (const float*)d_in[5];
    float* out = (float*)d_out;

    char* ws = (char*)d_ws;
    unsigned short* xb  = (unsigned short*)(ws);               // 16 MB (dead after gemm<0>)
    unsigned short* WT  = (unsigned short*)(ws + 16777216);    // 6 MB
    unsigned short* WoT = (unsigned short*)(ws + 23068672);    // 2 MB
    unsigned short* Qb  = (unsigned short*)(ws + 25165824);    // 16 MB
    unsigned short* Kb  = (unsigned short*)(ws + 41943040);    // 16 MB
    unsigned short* Vtb = (unsigned short*)(ws + 58720256);    // 16 MB (transposed)
    unsigned short* ctx = xb;                                  // alias: xb is dead

    prep<<<12288, 256, 0, stream>>>(x, xb, Wq, Wk, Wv, Wo, WT, WoT);
    gemm_bt<0, 24><<<1536, 256, 0, stream>>>(xb, WT, Qb, Kb, Vtb, nullptr, nullptr);
    attn<<<1024, 512, 0, stream>>>(Qb, Kb, Vtb, ctx);
    gemm_bt<1, 8><<<512, 256, 0, stream>>>(ctx, WoT, nullptr, nullptr, nullptr, bo, out);
}

// Round 6
// 231.542 us; speedup vs baseline: 1.5959x; 1.0083x over previous
//
#include <hip/hip_runtime.h>
#include <hip/hip_bf16.h>
#include <math.h>

// ---------------------------------------------------------------------------
// MultiHeadAttention: x[4,2048,1024] -> causal MHA (16 heads, d=64) -> out proj
// bf16 MFMA everywhere.
// R17: R16 base (verified 233.5us) + two independent levers:
// 1) gemm_bt: __launch_bounds__(256,3) -- 120 VGPR + 64 AGPR = 184 unified
//    regs capped waves at 2/SIMD (Occ 19%); <=170 gives 3/SIMD, more TLP to
//    absorb the end-of-step vmcnt(0) drain.
// 2) attn PV merged to 16x16x32: sigma-window pairs (2n1, 2n1+1) union to
//    the exact 16x16x32 B-frag (k = 8*quad + j), and the b128 V read is the
//    matching A-frag -> 8 MFMA/trip instead of 16x 16x16x16. + T5 setprio
//    around QK/PV MFMA clusters (~4 indep blocks/CU -> role diversity).
// ---------------------------------------------------------------------------

typedef __bf16  bf16x8  __attribute__((ext_vector_type(8)));
typedef __bf16  bf16x2  __attribute__((ext_vector_type(2)));
typedef float   floatx4 __attribute__((ext_vector_type(4)));
typedef short   shortx4 __attribute__((ext_vector_type(4)));

__device__ __forceinline__ unsigned short f2bf(float f) {
    __hip_bfloat16 h = __float2bfloat16(f);
    return *reinterpret_cast<unsigned short*>(&h);
}

// pack two f32 -> 2xbf16 in one dword (HW packed cvt when available)
__device__ __forceinline__ unsigned int pkbf(float a, float b) {
#if __has_builtin(__builtin_amdgcn_cvt_pk_bf16_f32)
    bf16x2 t = __builtin_amdgcn_cvt_pk_bf16_f32(a, b);
    return __builtin_bit_cast(unsigned int, t);
#else
    return (unsigned int)f2bf(a) | ((unsigned int)f2bf(b) << 16);
#endif
}
__device__ __forceinline__ ushort4 pk4(float a, float b, float c, float d) {
    union { ushort4 u; unsigned int w[2]; } u;
    u.w[0] = pkbf(a, b);
    u.w[1] = pkbf(c, d);
    return u.u;
}

// async global->LDS, 16 B per lane; LDS dest = wave-uniform base + lane*16
__device__ __forceinline__ void gll16(const unsigned short* g, unsigned short* l) {
    __builtin_amdgcn_global_load_lds(
        (const __attribute__((address_space(1))) unsigned int*)g,
        (__attribute__((address_space(3))) unsigned int*)l, 16, 0, 0);
}

// K LDS row permutation: lds row j holds global k-row pi(j),
// pi(j) = 32*(j>>5) + 4*((j>>4)&1) + 8*((j&15)>>2) + (j&3).
// krho = pi^{-1}: staging writes global row r into lds row krho(r).
// Verified bijective: pi(krho(r)) == r.
__device__ __forceinline__ int krho(int r) {
    return (r & 0x20) | ((r & 4) << 2) | ((r & 0x18) >> 1) | (r & 3);
}

// --------------------------------------------- fused convert x + transpose W
__global__ void prep(const float* __restrict__ x, unsigned short* __restrict__ xb,
                     const float* __restrict__ Wq, const float* __restrict__ Wk,
                     const float* __restrict__ Wv, const float* __restrict__ Wo,
                     unsigned short* __restrict__ WT, unsigned short* __restrict__ WoT) {
    __shared__ float tile[32][33];
    int bid = blockIdx.x, tid = threadIdx.x;
    if (bid < 8192) {
        int i = (bid * 256 + tid) * 4;
        float4 v = *(const float4*)(x + i);
        *(ushort4*)(xb + i) = pk4(v.x, v.y, v.z, v.w);
        return;
    }
    int id = bid - 8192;
    int mat = id >> 10, rem = id & 1023;
    const float* src = (mat == 0) ? Wq : (mat == 1) ? Wk : (mat == 2) ? Wv : Wo;
    unsigned short* dst = (mat < 3) ? WT : WoT;
    int nbase = (mat < 3) ? mat * 1024 : 0;
    int kt = (rem & 31) * 32, nt = (rem >> 5) * 32;
    int tx = tid & 31, ty = tid >> 5;  // 32 x 8
    for (int j = 0; j < 32; j += 8)
        tile[ty + j][tx] = src[(kt + ty + j) * 1024 + nt + tx];
    __syncthreads();
    for (int j = 0; j < 32; j += 8) {
        int n = nt + ty + j;
        dst[(nbase + n) * 1024 + kt + tx] = f2bf(tile[tx][ty + j]);
    }
}

// ---------------------------------------------------------------- GEMM B^T
// C[M,N] = A[M,1024] @ B^T (B stored [N][1024]). 128x128 tile, BK=64.
// Double-buffered gll16 staging (stage t+1 before compute t); XOR swizzle
// (0 bank conflicts). One __syncthreads per K-step.
// __launch_bounds__(256,3): cap unified VGPR+AGPR at <=170 -> 3 waves/SIMD.
// Flat grid + XCD-chunked bijective swizzle.
// Orientation: swapped (C^T) for Q/K columns (n0<2048) and all of EPI1.
template <int EPI, int NBLK>
__global__ __launch_bounds__(256, 3) void gemm_bt(const unsigned short* __restrict__ A,
                                                  const unsigned short* __restrict__ B,
                                                  unsigned short* __restrict__ Qo,
                                                  unsigned short* __restrict__ Ko,
                                                  unsigned short* __restrict__ Vo,
                                                  const float* __restrict__ bias,
                                                  float* __restrict__ Out) {
    __shared__ __align__(16) unsigned short As[2][128 * 64];
    __shared__ __align__(16) unsigned short Bs[2][128 * 64];

    int tid = threadIdx.x;
    int lane = tid & 63, w = tid >> 6;
    int wm = w >> 1, wn = w & 1;
    int lm = lane & 15, quad = lane >> 4;
    // T1 swizzle: bid&7 -> XCD chunk; within chunk m-fastest over the 8-band.
    int bid = blockIdx.x;
    int xcd = bid & 7, ic = bid >> 3;
    int bm = xcd * 8 + (ic & 7), bn = ic >> 3;  // bn in [0, NBLK)
    int m0 = bm * 128, n0 = bn * 128;
    bool sw = (EPI == 1) || (n0 < 2048);  // block-uniform orientation

    // stage one full 128x64 K-tile of A and B into buffer `buf`
    auto STAGE = [&](int buf, int kb) {
#pragma unroll
        for (int p = 0; p < 4; ++p) {
            int id = p * 256 + tid;
            int row = id >> 3;
            int cbs = ((id & 7) ^ (row & 7)) * 8;  // XOR-swizzled source unit
            int lbase = (p * 256 + w * 64) * 8;    // wave-uniform; HW adds lane*16B
            gll16(&A[(m0 + row) * 1024 + kb + cbs], &As[buf][lbase]);
            gll16(&B[(n0 + row) * 1024 + kb + cbs], &Bs[buf][lbase]);
        }
    };

    floatx4 acc[4][4] = {};

    STAGE(0, 0);
    __syncthreads();   // compiler drains vmcnt(0): tile 0 resident

#pragma unroll 2
    for (int t = 0; t < 16; ++t) {
        if (t < 15) STAGE((t + 1) & 1, (t + 1) * 64);  // loads fly under compute
        const unsigned short* Ac = &As[t & 1][0];
        const unsigned short* Bc = &Bs[t & 1][0];

        bf16x8 af[2][4], bf[2][4];
        for (int ks = 0; ks < 2; ++ks)
            for (int i = 0; i < 4; ++i) {
                int pu = (((ks * 4 + quad) ^ (lm & 7))) * 8;  // swizzled unit
                af[ks][i] = *(const bf16x8*)&Ac[(wm * 64 + i * 16 + lm) * 64 + pu];
                bf[ks][i] = *(const bf16x8*)&Bs[t & 1][(wn * 64 + i * 16 + lm) * 64 + pu];
            }
        if (sw) {
            for (int mi = 0; mi < 4; ++mi)
                for (int ni = 0; ni < 4; ++ni) {
                    acc[mi][ni] = __builtin_amdgcn_mfma_f32_16x16x32_bf16(bf[0][ni], af[0][mi], acc[mi][ni], 0, 0, 0);
                    acc[mi][ni] = __builtin_amdgcn_mfma_f32_16x16x32_bf16(bf[1][ni], af[1][mi], acc[mi][ni], 0, 0, 0);
                }
        } else {
            for (int mi = 0; mi < 4; ++mi)
                for (int ni = 0; ni < 4; ++ni) {
                    acc[mi][ni] = __builtin_amdgcn_mfma_f32_16x16x32_bf16(af[0][mi], bf[0][ni], acc[mi][ni], 0, 0, 0);
                    acc[mi][ni] = __builtin_amdgcn_mfma_f32_16x16x32_bf16(af[1][mi], bf[1][ni], acc[mi][ni], 0, 0, 0);
                }
        }
        // waits lgkmcnt(0) (ds_reads of buf[t&1] done -> safe to restage it
        // next iter) AND vmcnt(0) (buf[(t+1)&1] writes landed -> safe to read).
        __syncthreads();
    }

    if constexpr (EPI == 0) {
        if (sw) {
            // C^T layout: lane owns seq s (col=lm) and 4 consecutive out-cols.
            bool isQ = (n0 < 1024);
            unsigned short* dst = isQ ? Qo : Ko;
            float qs = isQ ? 0.1803368801f : 1.0f;  // 1/8 * log2(e)
            for (int mi = 0; mi < 4; ++mi) {
                int s = m0 + wm * 64 + mi * 16 + lm;
                int bb = s >> 11, sl = s & 2047;
                for (int ni = 0; ni < 4; ++ni) {
                    int gcol0 = n0 + wn * 64 + ni * 16 + quad * 4;
                    int h = (gcol0 & 1023) >> 6, d0 = gcol0 & 63;
                    *(ushort4*)&dst[(((size_t)(bb * 16 + h) * 2048) + sl) * 64 + d0] =
                        pk4(acc[mi][ni][0] * qs, acc[mi][ni][1] * qs,
                            acc[mi][ni][2] * qs, acc[mi][ni][3] * qs);
                }
            }
        } else {
            // V columns, normal layout: packed along seq for V^T [bh][d][2048].
            for (int mi = 0; mi < 4; ++mi) {
                int grow0 = m0 + wm * 64 + mi * 16 + quad * 4;
                int bb = grow0 >> 11, sl = grow0 & 2047;
                for (int ni = 0; ni < 4; ++ni) {
                    int gcol = n0 + wn * 64 + ni * 16 + lm;
                    int hn = gcol & 1023;
                    int h = hn >> 6, d = hn & 63;
                    *(ushort4*)&Vo[((size_t)(bb * 16 + h) * 64 + d) * 2048 + sl] =
                        pk4(acc[mi][ni][0], acc[mi][ni][1], acc[mi][ni][2], acc[mi][ni][3]);
                }
            }
        }
    } else {
        // out-proj: C^T layout -> float4 stores + float4 bias loads
        for (int mi = 0; mi < 4; ++mi) {
            int s = m0 + wm * 64 + mi * 16 + lm;
            for (int ni = 0; ni < 4; ++ni) {
                int gcol0 = n0 + wn * 64 + ni * 16 + quad * 4;
                float4 bv = *(const float4*)&bias[gcol0];
                float4 o;
                o.x = acc[mi][ni][0] + bv.x; o.y = acc[mi][ni][1] + bv.y;
                o.z = acc[mi][ni][2] + bv.z; o.w = acc[mi][ni][3] + bv.w;
                *(float4*)&Out[(size_t)s * 1024 + gcol0] = o;
            }
        }
    }
}

// ------------------------------------------------------------- attention
// Flat grid 1024 = (qt heavy-first, 16 tiles of 128 q) x 64 bh.
// 512 thr = 8 waves x 16 q-rows. KB=64. S^T orientation: q=lm.
// K lds rows permuted by krho so S^T rows follow
// sigma_n(m)=32(n>>1)+4(n&1)+8(m>>2)+(m&3). PV: window pair (2n1,2n1+1)
// unions to the exact 16x16x32 B-frag (k=8*quad+j) and the b128 V read is
// the matching A-frag -> 8 mfma_16x16x32 per trip (was 16x 16x16x16),
// conflict-free LDS. setprio(1) around MFMA clusters (T5).
// NO-MAX softmax; Q pre-scaled; lrow reduced once at the end.
__global__ __launch_bounds__(512) void attn(const unsigned short* __restrict__ Q,
                                            const unsigned short* __restrict__ K,
                                            const unsigned short* __restrict__ Vt,
                                            unsigned short* __restrict__ ctx) {
    constexpr int LKS = 72;
    __shared__ __align__(16) unsigned short Ks[2][64 * LKS];
    __shared__ __align__(16) unsigned short Vts[2][64 * LKS];

    int tid = threadIdx.x, lane = tid & 63, w = tid >> 6;   // w: 0..7
    int lm = lane & 15, quad = lane >> 4;
    int blk = blockIdx.x;
    int bh = blk & 63;
    int qt = 15 - (blk >> 6);   // LPT: heaviest q-tiles dispatch first
    int trips = 2 * qt + 2;
    int tmax = 2 * qt + (w >> 2);  // last trip this wave computes
    const unsigned short* Qg  = Q  + (size_t)bh * 2048 * 64;
    const unsigned short* Kg  = K  + (size_t)bh * 2048 * 64;
    const unsigned short* Vtg = Vt + (size_t)bh * 64 * 2048;

    int qrow = qt * 128 + w * 16 + lm;
    bf16x8 aq0 = *(const bf16x8*)&Qg[qrow * 64 + quad * 8];
    bf16x8 aq1 = *(const bf16x8*)&Qg[qrow * 64 + 32 + quad * 8];

    floatx4 O[4] = {};            // O^T: per dblk, lane holds d=quad*4+r, q=lm
    float lrow = 0.f;

    int r0 = tid >> 3, c0 = (tid & 7) * 8;  // 512 thr -> rows 0..63, 1 uint4 each
    int rK = krho(r0);                      // permuted K lds row

    {   // prologue: stage tile 0 into buffer 0
        uint4 k0 = *(const uint4*)&Kg[r0 * 64 + c0];
        uint4 v0 = *(const uint4*)&Vtg[r0 * 2048 + c0];
        *(uint4*)&Ks[0][rK * LKS + c0]  = k0;
        *(uint4*)&Vts[0][r0 * LKS + c0] = v0;
    }
    __syncthreads();

    for (int t = 0; t < trips; ++t) {
        int cur = t & 1, nxt = cur ^ 1;
        bool pre = (t + 1 < trips);
        uint4 pk, pv;
        if (pre) {  // issue next tile's loads NOW; they complete under compute
            int kb2 = (t + 1) * 64;
            pk = *(const uint4*)&Kg[(kb2 + r0) * 64 + c0];
            pv = *(const uint4*)&Vtg[r0 * 2048 + kb2 + c0];
        }

        if (t <= tmax) {  // wave-uniform; barriers are outside this branch
            const unsigned short* Kc = Ks[cur];
            const unsigned short* Vc = Vts[cur];

            floatx4 s[4];
            __builtin_amdgcn_s_setprio(1);
            for (int n = 0; n < 4; ++n) {
                bf16x8 a0 = *(const bf16x8*)&Kc[(n * 16 + lm) * LKS + quad * 8];
                bf16x8 a1 = *(const bf16x8*)&Kc[(n * 16 + lm) * LKS + 32 + quad * 8];
                floatx4 z = {};
                z = __builtin_amdgcn_mfma_f32_16x16x32_bf16(a0, aq0, z, 0, 0, 0);
                z = __builtin_amdgcn_mfma_f32_16x16x32_bf16(a1, aq1, z, 0, 0, 0);
                s[n] = z;
            }
            __builtin_amdgcn_s_setprio(0);

            bool diag = (t == tmax);
            if (diag) {
                int qr = (w & 3) * 16 + lm;  // q - kb on this wave's diag tile
                for (int n = 0; n < 4; ++n)
                    for (int r = 0; r < 4; ++r) {
                        int kin = (n >> 1) * 32 + (n & 1) * 4 + quad * 8 + r;
                        if (kin > qr) s[n][r] = -INFINITY;
                    }
            }
            float p[4][4], rs = 0.f;
            for (int n = 0; n < 4; ++n)
                for (int r = 0; r < 4; ++r) {
                    p[n][r] = __builtin_amdgcn_exp2f(s[n][r]);
                    rs += p[n][r];
                }
            lrow += rs;

            // P -> bf16; window pair (2n1,2n1+1) concatenates to the
            // 16x16x32 B-frag: lane holds k = 32n1 + 8*quad + j, j=0..7.
            unsigned int pw[4][2];
            for (int n = 0; n < 4; ++n) {
                pw[n][0] = pkbf(p[n][0], p[n][1]);
                pw[n][1] = pkbf(p[n][2], p[n][3]);
            }
            __builtin_amdgcn_s_setprio(1);
#pragma unroll
            for (int n1 = 0; n1 < 2; ++n1) {
                union { bf16x8 v; unsigned int wd[4]; } pu;
                pu.wd[0] = pw[2 * n1][0];     pu.wd[1] = pw[2 * n1][1];
                pu.wd[2] = pw[2 * n1 + 1][0]; pu.wd[3] = pw[2 * n1 + 1][1];
#pragma unroll
                for (int dblk = 0; dblk < 4; ++dblk) {
                    bf16x8 va = *(const bf16x8*)&Vc[(dblk * 16 + lm) * LKS + n1 * 32 + quad * 8];
                    O[dblk] = __builtin_amdgcn_mfma_f32_16x16x32_bf16(va, pu.v, O[dblk], 0, 0, 0);
                }
            }
            __builtin_amdgcn_s_setprio(0);
        }

        if (pre) {  // loads completed under compute; write into other buffer
            *(uint4*)&Ks[nxt][rK * LKS + c0]  = pk;
            *(uint4*)&Vts[nxt][r0 * LKS + c0] = pv;
        }
        __syncthreads();
    }

    // reduce lrow across the 4 lane-groups holding the same q (once)
    lrow += __shfl_xor(lrow, 16);
    lrow += __shfl_xor(lrow, 32);

    int b = bh >> 4, h = bh & 15;
    int q = qt * 128 + w * 16 + lm;
    float inv = 1.0f / lrow;
    for (int dblk = 0; dblk < 4; ++dblk) {
        *(ushort4*)&ctx[((size_t)(b * 2048 + q)) * 1024 + h * 64 + dblk * 16 + quad * 4] =
            pk4(O[dblk][0] * inv, O[dblk][1] * inv, O[dblk][2] * inv, O[dblk][3] * inv);
    }
}

// ---------------------------------------------------------------- launch
extern "C" void kernel_launch(void* const* d_in, const int* in_sizes, int n_in,
                              void* d_out, int out_size, void* d_ws, size_t ws_size,
                              hipStream_t stream) {
    const float* x   = (const float*)d_in[0];
    const float* Wq  = (const float*)d_in[1];
    const float* Wk  = (const float*)d_in[2];
    const float* Wv  = (const float*)d_in[3];
    const float* Wo  = (const float*)d_in[4];
    const float* bo  = (const float*)d_in[5];
    float* out = (float*)d_out;

    char* ws = (char*)d_ws;
    unsigned short* xb  = (unsigned short*)(ws);               // 16 MB (dead after gemm<0>)
    unsigned short* WT  = (unsigned short*)(ws + 16777216);    // 6 MB
    unsigned short* WoT = (unsigned short*)(ws + 23068672);    // 2 MB
    unsigned short* Qb  = (unsigned short*)(ws + 25165824);    // 16 MB
    unsigned short* Kb  = (unsigned short*)(ws + 41943040);    // 16 MB
    unsigned short* Vtb = (unsigned short*)(ws + 58720256);    // 16 MB (transposed)
    unsigned short* ctx = xb;                                  // alias: xb is dead

    prep<<<12288, 256, 0, stream>>>(x, xb, Wq, Wk, Wv, Wo, WT, WoT);
    gemm_bt<0, 24><<<1536, 256, 0, stream>>>(xb, WT, Qb, Kb, Vtb, nullptr, nullptr);
    attn<<<1024, 512, 0, stream>>>(Qb, Kb, Vtb, ctx);
    gemm_bt<1, 8><<<512, 256, 0, stream>>>(ctx, WoT, nullptr, nullptr, nullptr, bo, out);
}